// Round 13
// baseline (807.934 us; speedup 1.0000x reference)
//
#include <hip/hip_runtime.h>

#define B_  8
#define N_  2048
#define M_  16384
#define KNN 20
#define NEG 0.2f

__device__ __forceinline__ unsigned enc_f(float f) {
    unsigned u = __float_as_uint(f);
    return (u & 0x80000000u) ? ~u : (u | 0x80000000u);
}
__device__ __forceinline__ float dec_f(unsigned u) {
    return (u & 0x80000000u) ? __uint_as_float(u & 0x7FFFFFFFu) : __uint_as_float(~u);
}
__device__ __forceinline__ unsigned long long mkkey(unsigned e, unsigned j) {
    return ((unsigned long long)e << 32) | j;
}
// bf16 round-to-nearest-even of fp32
__device__ __forceinline__ unsigned short bf_hi(float a) {
    unsigned u = __float_as_uint(a);
    unsigned r = u + 0x7FFFu + ((u >> 16) & 1u);
    return (unsigned short)(r >> 16);
}
__device__ __forceinline__ float bf_f(unsigned short h) {
    return __uint_as_float((unsigned)h << 16);
}

// ---------------- fused weight-prep mega-kernel ----------------
__device__ __forceinline__ void wstack_body(const float* __restrict__ w, float* __restrict__ ws,
                                            int O, int Cc, int Kp, int i) {
    if (i >= 2 * O * Kp) return;
    int row = i / Kp, k = i - row * Kp;
    float v = 0.f;
    if (k < Cc) {
        int o = (row < O) ? row : row - O;
        float w1 = w[(size_t)o * 2 * Cc + k];
        v = (row < O) ? w1 : (w[(size_t)o * 2 * Cc + Cc + k] - w1);
    }
    ws[i] = v;
}
__device__ __forceinline__ void wsplit_body(const float* __restrict__ w, int ldin,
                                            unsigned short* __restrict__ h, unsigned short* __restrict__ l,
                                            int Kshift, int i) {
    int row = i >> Kshift, k = i & ((1 << Kshift) - 1);
    float v = w[(size_t)row * ldin + k];
    unsigned short hi = bf_hi(v);
    h[i] = hi;
    l[i] = bf_hi(v - bf_f(hi));
}
// ec4 stacked weight, split directly (rows [0,256)=W1, [256,512)=W2-W1, K=128)
__device__ __forceinline__ void wstacksplit_body(const float* __restrict__ w,
                                                 unsigned short* __restrict__ h, unsigned short* __restrict__ l,
                                                 int i) {
    int row = i >> 7, k = i & 127;
    int o = (row < 256) ? row : row - 256;
    float w1 = w[(size_t)o * 256 + k];
    float v = (row < 256) ? w1 : (w[(size_t)o * 256 + 128 + k] - w1);
    unsigned short hi = bf_hi(v);
    h[i] = hi;
    l[i] = bf_hi(v - bf_f(hi));
}

__global__ void prep_weights_kernel(
        const float* __restrict__ ec1_w, const float* __restrict__ ec2_w,
        const float* __restrict__ ec3_w, const float* __restrict__ ec4_w,
        const float* __restrict__ fuse_w, const float* __restrict__ emb_w,
        const float* __restrict__ h1_w, const float* __restrict__ h2_w,
        float* __restrict__ ws1, float* __restrict__ ws2, float* __restrict__ ws3,
        unsigned short* __restrict__ ws4_h, unsigned short* __restrict__ ws4_l,
        unsigned short* __restrict__ fuse_h, unsigned short* __restrict__ fuse_l,
        unsigned short* __restrict__ emb_h, unsigned short* __restrict__ emb_l,
        unsigned short* __restrict__ h1_h, unsigned short* __restrict__ h1_l,
        unsigned short* __restrict__ h2_h, unsigned short* __restrict__ h2_l,
        unsigned* __restrict__ gmax) {
    int blk = blockIdx.x, tid = threadIdx.x;
    if (blk < 8)            { wstack_body(ec1_w, ws1, 64, 3, 16, blk * 256 + tid); }
    else if (blk < 40)      { wstack_body(ec2_w, ws2, 64, 64, 64, (blk - 8) * 256 + tid); }
    else if (blk < 104)     { wstack_body(ec3_w, ws3, 128, 64, 64, (blk - 40) * 256 + tid); }
    else if (blk < 360)     { wstacksplit_body(ec4_w, ws4_h, ws4_l, (blk - 104) * 256 + tid); }
    else if (blk < 1384)    { wsplit_body(fuse_w, 512, fuse_h, fuse_l, 9, (blk - 360) * 256 + tid); }
    else if (blk < 3432)    { wsplit_body(emb_w, 512, emb_h, emb_l, 9, (blk - 1384) * 256 + tid); }
    else if (blk < 3944)    { wsplit_body(h1_w, 1536, h1_h, h1_l, 9, (blk - 3432) * 256 + tid); }
    else if (blk < 4200)    { wsplit_body(h2_w, 256, h2_h, h2_l, 8, (blk - 3944) * 256 + tid); }
    else                    { int i = (blk - 4200) * 256 + tid;
                              if (i < B_ * 1024) gmax[i] = enc_f(-1e30f); }
}

// xx[m] = ||x_m||^2 ; xt[b][c][n] = x[m][c]
template<int C>
__global__ void prep_kernel(const float* __restrict__ x, int lda,
                            float* __restrict__ xx, float* __restrict__ xt) {
    int m = blockIdx.x * 256 + threadIdx.x;
    if (m >= M_) return;
    int b = m >> 11, n = m & 2047;
    const float* row = x + (size_t)m * lda;
    float s = 0.f;
#pragma unroll 8
    for (int c = 0; c < C; ++c) {
        float v = row[c];
        s = fmaf(v, v, s);
        xt[((size_t)b * C + c) * N_ + n] = v;
    }
    xx[m] = s;
}

// One block (512 thr) = 16 query rows x 2048 cols, 4 cols/thread:
// 64 fma per xtv-load quad (~94% issue ceiling) and 2x L2 reuse vs RM=8.
// Query-row features via wave-uniform scalar loads (R12, verified). Explicit
// cur/nxt load double-buffer so the allocator cannot serialize (R11 lesson).
// No per-thread key array (spill-proof); enc keys recomputed on demand
// (bit-identical chain; dropping zero-pad fmas is exact: fmaf(0,v,a)==a).
// Selection = verified stages A-D; m4s and cand UNION one 32 KB buffer
// (m4s dead after stage B).
#define RM 16
template<int C>
__global__ __launch_bounds__(512, 4) void dist_topk_kernel(
        const float* __restrict__ xt, const float* __restrict__ xx,
        int* __restrict__ idxout) {
    __shared__ unsigned smem[RM][512];            // 32 KB: m4s, then cand
    __shared__ int cnt[RM];
    __shared__ unsigned tub[RM];
    int blk = blockIdx.x;
    int b = blk >> 7;                             // 128 blocks per batch
    int i0 = (blk & 127) * RM;
    int tid = threadIdx.x;
    int lane = tid & 63, w = tid >> 6;
    const float* xtb = xt + (size_t)b * C * N_;
    const float* xxb = xx + (size_t)b * N_;

    if (tid < RM) cnt[tid] = 0;
    __syncthreads();

    float xxir[RM];
#pragma unroll
    for (int q = 0; q < RM; ++q) xxir[q] = xxb[i0 + q];   // uniform -> s_load
    float xxj[4];
#pragma unroll
    for (int p = 0; p < 4; ++p) xxj[p] = xxb[tid + 512 * p];

    // ---- compute: 4 cols/thread x 16 rows (fmaf chain ascending in c)
    float acc[RM][4];
#pragma unroll
    for (int q = 0; q < RM; ++q)
#pragma unroll
        for (int p = 0; p < 4; ++p) acc[q][p] = 0.f;

    float cur[4], nxt[4];
#pragma unroll
    for (int p = 0; p < 4; ++p) cur[p] = xtb[tid + 512 * p];  // c = 0
#pragma unroll 2
    for (int c = 0; c < C; ++c) {
        if (c + 1 < C) {
#pragma unroll
            for (int p = 0; p < 4; ++p)
                nxt[p] = xtb[(size_t)(c + 1) * N_ + tid + 512 * p];
        }
#pragma unroll
        for (int q = 0; q < RM; ++q) {
            float a = xtb[(size_t)c * N_ + i0 + q];           // uniform -> SGPR
#pragma unroll
            for (int p = 0; p < 4; ++p) acc[q][p] = fmaf(a, cur[p], acc[q][p]);
        }
#pragma unroll
        for (int p = 0; p < 4; ++p) cur[p] = nxt[p];
    }

    // ---- A: per-thread group min (keys recomputed, never stored)
#pragma unroll
    for (int q = 0; q < RM; ++q) {
        unsigned m = 0xFFFFFFFFu;
#pragma unroll
        for (int p = 0; p < 4; ++p) {
            unsigned e = enc_f(xxir[q] + xxj[p] - 2.f * acc[q][p]);
            m = (e < m) ? e : m;
        }
        smem[q][tid] = m;
    }
    __syncthreads();

    // ---- B: wave w -> rows 2w, 2w+1; Tub = 20th-smallest lane-min
    for (int rr = 0; rr < 2; ++rr) {
        int q = 2 * w + rr;
        unsigned lmin = 0xFFFFFFFFu;
#pragma unroll
        for (int i = 0; i < 8; ++i) {
            unsigned v = smem[q][lane + 64 * i];
            lmin = (v < lmin) ? v : lmin;
        }
        unsigned T = 0u;
        for (int bpos = 31; bpos >= 0; --bpos) {
            unsigned cd = T | (1u << bpos);
            unsigned long long bal = __ballot(lmin < cd);
            if ((int)__popcll(bal) < KNN) T = cd;
        }
        if (lane == 0) tub[q] = T;
    }
    __syncthreads();   // all m4s reads done; smem may be reused as cand

    unsigned long long* cand0 = (unsigned long long*)&smem[0][0];
    // cand row q occupies [q*128, q*128+128) u64 slots (16 KB of the 32)

    // ---- C: append candidates (e <= Tub[row]); expected ~24 per row
#pragma unroll
    for (int q = 0; q < RM; ++q) {
        unsigned Tq = tub[q];
#pragma unroll
        for (int p = 0; p < 4; ++p) {
            unsigned e = enc_f(xxir[q] + xxj[p] - 2.f * acc[q][p]);
            if (e <= Tq) {
                int pos = atomicAdd(&cnt[q], 1);
                if (pos < 128)
                    cand0[q * 128 + pos] = mkkey(e, (unsigned)(tid + 512 * p));
            }
        }
    }
    __syncthreads();

    // ---- D: rank candidates; winners fill slots 0..19 exactly
    for (int rr = 0; rr < 2; ++rr) {
        int q = 2 * w + rr;
        int A = cnt[q];
        if (A > 128) A = 128;   // unreachable on continuous data (guarded)
        int* orow = idxout + (size_t)(b * N_ + i0 + q) * KNN;
        for (int cc = lane; cc < A; cc += 64) {
            unsigned long long mykey = cand0[q * 128 + cc];
            int rank = 0;
            for (int i = 0; i < A; ++i)
                rank += (cand0[q * 128 + i] < mykey) ? 1 : 0;
            if (rank < KNN) orow[rank] = (int)(mykey & 2047u);
        }
    }
}

// ---------------- MFMA split-bf16 GEMM ----------------
typedef __attribute__((ext_vector_type(8))) short short8;
typedef __attribute__((ext_vector_type(4))) float f32x4;

template<int MODE>
__global__ __launch_bounds__(256, 2) void mgemm_kernel(
        const float* __restrict__ A, int lda,
        const unsigned short* __restrict__ Bh, const unsigned short* __restrict__ Bl, int ldw,
        float* __restrict__ out, int ldo,
        const float* __restrict__ sc, const float* __restrict__ sh,
        const float* __restrict__ addvec, unsigned* __restrict__ gmax,
        int K, int O) {
    __shared__ unsigned short Ah_s[128][40];
    __shared__ unsigned short Al_s[128][40];
    __shared__ unsigned short Bh_s[128][40];
    __shared__ unsigned short Bl_s[128][40];
    int tid = threadIdx.x;
    int lane = tid & 63, w = tid >> 6;
    int ln = lane & 15, kg = lane >> 4;
    int wm = (w >> 1) * 64, wn = (w & 1) * 64;
    int m0 = blockIdx.y * 128, o0 = blockIdx.x * 128;
    f32x4 acc[4][4] = {};

    for (int k0 = 0; k0 < K; k0 += 32) {
#pragma unroll
        for (int j = 0; j < 4; ++j) {
            int s = tid + j * 256;
            int row = s >> 3, q = s & 7;
            float4 v = *(const float4*)&A[(size_t)(m0 + row) * lda + k0 + q * 4];
            unsigned short h0 = bf_hi(v.x), h1 = bf_hi(v.y), h2 = bf_hi(v.z), h3 = bf_hi(v.w);
            unsigned short l0 = bf_hi(v.x - bf_f(h0)), l1 = bf_hi(v.y - bf_f(h1));
            unsigned short l2 = bf_hi(v.z - bf_f(h2)), l3 = bf_hi(v.w - bf_f(h3));
            *(uint2*)&Ah_s[row][q * 4] = make_uint2((unsigned)h0 | ((unsigned)h1 << 16),
                                                    (unsigned)h2 | ((unsigned)h3 << 16));
            *(uint2*)&Al_s[row][q * 4] = make_uint2((unsigned)l0 | ((unsigned)l1 << 16),
                                                    (unsigned)l2 | ((unsigned)l3 << 16));
        }
#pragma unroll
        for (int j = 0; j < 2; ++j) {
            int s = tid + j * 256;
            int row = s >> 2, q = s & 3;
            *(uint4*)&Bh_s[row][q * 8] = *(const uint4*)&Bh[(size_t)(o0 + row) * ldw + k0 + q * 8];
            *(uint4*)&Bl_s[row][q * 8] = *(const uint4*)&Bl[(size_t)(o0 + row) * ldw + k0 + q * 8];
        }
        __syncthreads();

        short8 ah[4], al[4], bh[4], bl[4];
#pragma unroll
        for (int t = 0; t < 4; ++t) {
            ah[t] = *(const short8*)&Ah_s[wm + t * 16 + ln][kg * 8];
            al[t] = *(const short8*)&Al_s[wm + t * 16 + ln][kg * 8];
            bh[t] = *(const short8*)&Bh_s[wn + t * 16 + ln][kg * 8];
            bl[t] = *(const short8*)&Bl_s[wn + t * 16 + ln][kg * 8];
        }
#pragma unroll
        for (int t = 0; t < 4; ++t)
#pragma unroll
            for (int u = 0; u < 4; ++u) {
                acc[t][u] = __builtin_amdgcn_mfma_f32_16x16x32_bf16(ah[t], bh[u], acc[t][u], 0, 0, 0);
                acc[t][u] = __builtin_amdgcn_mfma_f32_16x16x32_bf16(ah[t], bl[u], acc[t][u], 0, 0, 0);
                acc[t][u] = __builtin_amdgcn_mfma_f32_16x16x32_bf16(al[t], bh[u], acc[t][u], 0, 0, 0);
            }
        __syncthreads();
    }

    int b = m0 >> 11;
    if constexpr (MODE == 3) {
#pragma unroll
        for (int u = 0; u < 4; ++u) {
            int o = o0 + wn + u * 16 + ln;
            float s = sc[o], t0 = sh[o];
            float cm = -1e30f;
#pragma unroll
            for (int t = 0; t < 4; ++t)
#pragma unroll
                for (int p = 0; p < 4; ++p) {
                    float v = fmaf(acc[t][u][p], s, t0);
                    v = (v >= 0.f) ? v : NEG * v;
                    cm = fmaxf(cm, v);
                }
            cm = fmaxf(cm, __shfl_xor(cm, 16));
            cm = fmaxf(cm, __shfl_xor(cm, 32));
            if (kg == 0) atomicMax(&gmax[b * 1024 + o], enc_f(cm));
        }
        return;
    }
#pragma unroll
    for (int t = 0; t < 4; ++t)
#pragma unroll
        for (int p = 0; p < 4; ++p) {
            int m = m0 + wm + t * 16 + kg * 4 + p;
#pragma unroll
            for (int u = 0; u < 4; ++u) {
                int o = o0 + wn + u * 16 + ln;
                float v = acc[t][u][p];
                if (MODE == 1) {
                    if (addvec) v += addvec[b * O + o];
                    v = fmaf(v, sc[o], sh[o]);
                    v = (v >= 0.f) ? v : NEG * v;
                }
                out[(size_t)m * ldo + o] = v;
            }
        }
}

// ---------------- fp32 GEMM (ec1..ec3, h3) ----------------
template<int TN, int MODE, bool VEC>
__global__ __launch_bounds__(256, 4) void gemm_kernel(
        const float* __restrict__ A, int lda,
        const float* __restrict__ W, int ldw,
        float* __restrict__ out, int ldo,
        const float* __restrict__ sc, const float* __restrict__ sh,
        const float* __restrict__ addvec, unsigned* __restrict__ gmax,
        int K, int O) {
    constexpr int TM = 128;
    constexpr int JN = TN / 16;
    __shared__ float As[16][TM];
    __shared__ float Bs[16][TN];
    int tid = threadIdx.x;
    int tx = tid & 15, ty = tid >> 4;
    int o0 = blockIdx.x * TN, m0 = blockIdx.y * TM;
    float acc[8][JN] = {};

    for (int k0 = 0; k0 < K; k0 += 16) {
        if constexpr (VEC) {
#pragma unroll
            for (int s = 0; s < 2; ++s) {
                int t = tid + s * 256;
                int row = t >> 2, c4 = (t & 3) << 2;
                float4 v = *(const float4*)&A[(size_t)(m0 + row) * lda + k0 + c4];
                As[c4 + 0][row] = v.x; As[c4 + 1][row] = v.y;
                As[c4 + 2][row] = v.z; As[c4 + 3][row] = v.w;
            }
#pragma unroll
            for (int s = 0; s < TN / 64; ++s) {
                int t = tid + s * 256;
                int row = t >> 2, c4 = (t & 3) << 2;
                int o = o0 + row;
                float4 v = make_float4(0.f, 0.f, 0.f, 0.f);
                if (o < O) v = *(const float4*)&W[(size_t)o * ldw + k0 + c4];
                Bs[c4 + 0][row] = v.x; Bs[c4 + 1][row] = v.y;
                Bs[c4 + 2][row] = v.z; Bs[c4 + 3][row] = v.w;
            }
        } else {
            for (int t = tid; t < TM * 16; t += 256) {
                int row = t >> 4, k = t & 15;
                As[k][row] = (k0 + k < K) ? A[(size_t)(m0 + row) * lda + k0 + k] : 0.f;
            }
            for (int t = tid; t < TN * 16; t += 256) {
                int row = t >> 4, k = t & 15;
                Bs[k][row] = W[(size_t)(o0 + row) * ldw + k0 + k];
            }
        }
        __syncthreads();
#pragma unroll
        for (int kk = 0; kk < 16; ++kk) {
            float a[8], bv[JN];
            *(float4*)&a[0] = *(const float4*)&As[kk][ty * 8];
            *(float4*)&a[4] = *(const float4*)&As[kk][ty * 8 + 4];
            *(float4*)&bv[0] = *(const float4*)&Bs[kk][tx * JN];
            if (JN == 8) *(float4*)&bv[4] = *(const float4*)&Bs[kk][tx * JN + 4];
#pragma unroll
            for (int i = 0; i < 8; ++i)
#pragma unroll
                for (int j = 0; j < JN; ++j)
                    acc[i][j] = fmaf(a[i], bv[j], acc[i][j]);
        }
        __syncthreads();
    }

    int b = m0 >> 11;
    bool fullstore = (o0 + TN <= O) && ((ldo & 3) == 0);
#pragma unroll
    for (int i = 0; i < 8; ++i) {
        int m = m0 + ty * 8 + i;
        float vals[JN];
#pragma unroll
        for (int j = 0; j < JN; ++j) {
            int o = o0 + tx * JN + j;
            float v = acc[i][j];
            if (MODE == 1) {
                if (addvec) v += addvec[b * O + o];
                v = fmaf(v, sc[o], sh[o]);
                v = (v >= 0.f) ? v : NEG * v;
            } else if (MODE == 2) {
                v += sh[o];
            }
            vals[j] = v;
        }
        if (fullstore) {
#pragma unroll
            for (int j0 = 0; j0 < JN; j0 += 4)
                *(float4*)&out[(size_t)m * ldo + o0 + tx * JN + j0] = *(float4*)&vals[j0];
        } else {
#pragma unroll
            for (int j = 0; j < JN; ++j) {
                int o = o0 + tx * JN + j;
                if (o < O) out[(size_t)m * ldo + o] = vals[j];
            }
        }
    }
}

// out[m][o..o+3] = max_k lrelu((y[nbr_k] + z[m]) * sc + sh); y/z packed in yz.
__global__ void edge_max_kernel(const float* __restrict__ yz, const int* __restrict__ idx,
                                const float* __restrict__ sc, const float* __restrict__ sh,
                                float* __restrict__ out, int ldo, int oshift) {
    int gid = blockIdx.x * 256 + threadIdx.x;
    int O = 1 << oshift;
    int m = gid >> (oshift - 2);
    int o = (gid & ((1 << (oshift - 2)) - 1)) << 2;
    int ldyz = 2 * O;
    float4 z = *(const float4*)&yz[(size_t)m * ldyz + O + o];
    float4 s4 = *(const float4*)&sc[o];
    float4 t4 = *(const float4*)&sh[o];
    const int* ip = idx + (size_t)m * KNN;
    int bbase = m & ~(N_ - 1);
    float4 mv = make_float4(-1e30f, -1e30f, -1e30f, -1e30f);
#pragma unroll
    for (int kk = 0; kk < KNN; ++kk) {
        int j = ip[kk];
        float4 y = *(const float4*)&yz[(size_t)(bbase + j) * ldyz + o];
        float v;
        v = fmaf(y.x + z.x, s4.x, t4.x); v = (v >= 0.f) ? v : NEG * v; mv.x = fmaxf(mv.x, v);
        v = fmaf(y.y + z.y, s4.y, t4.y); v = (v >= 0.f) ? v : NEG * v; mv.y = fmaxf(mv.y, v);
        v = fmaf(y.z + z.z, s4.z, t4.z); v = (v >= 0.f) ? v : NEG * v; mv.z = fmaxf(mv.z, v);
        v = fmaf(y.w + z.w, s4.w, t4.w); v = (v >= 0.f) ? v : NEG * v; mv.w = fmaxf(mv.w, v);
    }
    *(float4*)&out[(size_t)m * ldo + o] = mv;
}

// corr[b][o] = sum_c dec(gmax[b][c]) * h1w[o][512+c]   (decode folded in)
__global__ void corr_kernel(const unsigned* __restrict__ gmax, const float* __restrict__ h1w,
                            float* __restrict__ corr) {
    int wid = (blockIdx.x * 256 + threadIdx.x) >> 6;
    int lane = threadIdx.x & 63;
    int b = wid >> 8, o = wid & 255;
    const unsigned* g = gmax + b * 1024;
    const float* w = h1w + (size_t)o * 1536 + 512;
    float s = 0.f;
    for (int c = lane; c < 1024; c += 64) s = fmaf(dec_f(g[c]), w[c], s);
#pragma unroll
    for (int off = 32; off >= 1; off >>= 1) s += __shfl_xor(s, off);
    if (lane == 0) corr[b * 256 + o] = s;
}

extern "C" void kernel_launch(void* const* d_in, const int* in_sizes, int n_in,
                              void* d_out, int out_size, void* d_ws, size_t ws_size,
                              hipStream_t stream) {
    const float* xyz    = (const float*)d_in[0];
    const float* ec1_w  = (const float*)d_in[1];
    const float* ec1_s  = (const float*)d_in[2];
    const float* ec1_t  = (const float*)d_in[3];
    const float* ec2_w  = (const float*)d_in[4];
    const float* ec2_s  = (const float*)d_in[5];
    const float* ec2_t  = (const float*)d_in[6];
    const float* ec3_w  = (const float*)d_in[7];
    const float* ec3_s  = (const float*)d_in[8];
    const float* ec3_t  = (const float*)d_in[9];
    const float* ec4_w  = (const float*)d_in[10];
    const float* ec4_s  = (const float*)d_in[11];
    const float* ec4_t  = (const float*)d_in[12];
    const float* fuse_w = (const float*)d_in[13];
    const float* fuse_s = (const float*)d_in[14];
    const float* fuse_t = (const float*)d_in[15];
    const float* emb_w  = (const float*)d_in[16];
    const float* emb_s  = (const float*)d_in[17];
    const float* emb_t  = (const float*)d_in[18];
    const float* h1_w   = (const float*)d_in[19];
    const float* h1_s   = (const float*)d_in[20];
    const float* h1_t   = (const float*)d_in[21];
    const float* h2_w   = (const float*)d_in[22];
    const float* h2_s   = (const float*)d_in[23];
    const float* h2_t   = (const float*)d_in[24];
    const float* h3_w   = (const float*)d_in[25];
    const float* h3_b   = (const float*)d_in[26];
    float* out = (float*)d_out;

    float* ws = (float*)d_ws;
    size_t off = 0;
    float* xcat = ws + off; off += (size_t)M_ * 512;
    float* xloc = ws + off; off += (size_t)M_ * 512;
    float* yz   = ws + off; off += (size_t)M_ * 512;
    float* xt   = ws + off; off += (size_t)B_ * 128 * N_;
    float* xx   = ws + off; off += M_;
    int*   idx  = (int*)(ws + off); off += (size_t)M_ * KNN;
    float* ws1  = ws + off; off += 2 * 64 * 16;
    float* ws2  = ws + off; off += 2 * 64 * 64;
    float* ws3  = ws + off; off += 2 * 128 * 64;
    unsigned* gmax = (unsigned*)(ws + off); off += B_ * 1024;
    float* corr = ws + off; off += B_ * 256;
    unsigned short* fuse_h = (unsigned short*)(ws + off); off += 512 * 512 / 2;
    unsigned short* fuse_l = (unsigned short*)(ws + off); off += 512 * 512 / 2;
    unsigned short* emb_h  = (unsigned short*)(ws + off); off += 1024 * 512 / 2;
    unsigned short* emb_l  = (unsigned short*)(ws + off); off += 1024 * 512 / 2;
    unsigned short* h1_h   = (unsigned short*)(ws + off); off += 256 * 512 / 2;
    unsigned short* h1_l   = (unsigned short*)(ws + off); off += 256 * 512 / 2;
    unsigned short* h2_h   = (unsigned short*)(ws + off); off += 256 * 256 / 2;
    unsigned short* h2_l   = (unsigned short*)(ws + off); off += 256 * 256 / 2;
    unsigned short* ws4_h  = (unsigned short*)(ws + off); off += 512 * 128 / 2;
    unsigned short* ws4_l  = (unsigned short*)(ws + off); off += 512 * 128 / 2;
    float* h1o  = yz;                       // reuse after ec4's edge_max
    float* h2o  = yz + (size_t)M_ * 256;

    // ---- all weight prep + gmax init in ONE launch
    prep_weights_kernel<<<4232, 256, 0, stream>>>(
        ec1_w, ec2_w, ec3_w, ec4_w, fuse_w, emb_w, h1_w, h2_w,
        ws1, ws2, ws3, ws4_h, ws4_l, fuse_h, fuse_l, emb_h, emb_l,
        h1_h, h1_l, h2_h, h2_l, gmax);

    // ---- EdgeConv 1: xyz (C=3) -> xcat[:, 0:64]   (fp32 path, exact)
    prep_kernel<3><<<M_ / 256, 256, 0, stream>>>(xyz, 3, xx, xt);
    dist_topk_kernel<3><<<M_ / RM, 512, 0, stream>>>(xt, xx, idx);
    gemm_kernel<128, 0, false><<<dim3(1, M_ / 128), 256, 0, stream>>>(xyz, 3, ws1, 16, yz, 128, nullptr, nullptr, nullptr, nullptr, 3, 128);
    edge_max_kernel<<<(M_ * 16) / 256, 256, 0, stream>>>(yz, idx, ec1_s, ec1_t, xcat + 0, 512, 6);

    // ---- EdgeConv 2
    prep_kernel<64><<<M_ / 256, 256, 0, stream>>>(xcat + 0, 512, xx, xt);
    dist_topk_kernel<64><<<M_ / RM, 512, 0, stream>>>(xt, xx, idx);
    gemm_kernel<64, 0, true><<<dim3(2, M_ / 128), 256, 0, stream>>>(xcat + 0, 512, ws2, 64, yz, 128, nullptr, nullptr, nullptr, nullptr, 64, 128);
    edge_max_kernel<<<(M_ * 16) / 256, 256, 0, stream>>>(yz, idx, ec2_s, ec2_t, xcat + 64, 512, 6);

    // ---- EdgeConv 3
    prep_kernel<64><<<M_ / 256, 256, 0, stream>>>(xcat + 64, 512, xx, xt);
    dist_topk_kernel<64><<<M_ / RM, 512, 0, stream>>>(xt, xx, idx);
    gemm_kernel<128, 0, true><<<dim3(2, M_ / 128), 256, 0, stream>>>(xcat + 64, 512, ws3, 64, yz, 256, nullptr, nullptr, nullptr, nullptr, 64, 256);
    edge_max_kernel<<<(M_ * 32) / 256, 256, 0, stream>>>(yz, idx, ec3_s, ec3_t, xcat + 128, 512, 7);

    // ---- EdgeConv 4 (gemm output feeds no KNN -> MFMA-safe)
    prep_kernel<128><<<M_ / 256, 256, 0, stream>>>(xcat + 128, 512, xx, xt);
    dist_topk_kernel<128><<<M_ / RM, 512, 0, stream>>>(xt, xx, idx);
    mgemm_kernel<0><<<dim3(4, M_ / 128), 256, 0, stream>>>(xcat + 128, 512, ws4_h, ws4_l, 128, yz, 512, nullptr, nullptr, nullptr, nullptr, 128, 512);
    edge_max_kernel<<<(M_ * 64) / 256, 256, 0, stream>>>(yz, idx, ec4_s, ec4_t, xcat + 256, 512, 8);

    // ---- fuse: xcat(512) -> x_local(512), lrelu  [MFMA split-bf16]
    mgemm_kernel<1><<<dim3(4, M_ / 128), 256, 0, stream>>>(xcat, 512, fuse_h, fuse_l, 512, xloc, 512, fuse_s, fuse_t, nullptr, nullptr, 512, 512);

    // ---- emb: x_local -> (max over N) gmax  [MFMA split-bf16 + atomicMax]
    mgemm_kernel<3><<<dim3(8, M_ / 128), 256, 0, stream>>>(xloc, 512, emb_h, emb_l, 512, nullptr, 0, emb_s, emb_t, nullptr, gmax, 512, 1024);
    corr_kernel<<<512, 256, 0, stream>>>(gmax, h1_w, corr);

    // ---- h1: [x_local | glob] -> 256 ; glob part via corr  [MFMA]
    mgemm_kernel<1><<<dim3(2, M_ / 128), 256, 0, stream>>>(xloc, 512, h1_h, h1_l, 512, h1o, 256, h1_s, h1_t, corr, nullptr, 512, 256);
    // ---- h2: 256 -> 256  [MFMA]
    mgemm_kernel<1><<<dim3(2, M_ / 128), 256, 0, stream>>>(h1o, 256, h2_h, h2_l, 256, h2o, 256, h2_s, h2_t, nullptr, nullptr, 256, 256);
    // ---- h3: 256 -> 13 (+bias)  [fp32]
    gemm_kernel<64, 2, true><<<dim3(1, M_ / 128), 256, 0, stream>>>(h2o, 256, h3_w, 256, out, 13, nullptr, h3_b, nullptr, nullptr, 256, 13);
}

// Round 14
// 743.207 us; speedup vs baseline: 1.0871x; 1.0871x over previous
//
#include <hip/hip_runtime.h>

#define B_  8
#define N_  2048
#define M_  16384
#define KNN 20
#define NEG 0.2f

__device__ __forceinline__ unsigned enc_f(float f) {
    unsigned u = __float_as_uint(f);
    return (u & 0x80000000u) ? ~u : (u | 0x80000000u);
}
__device__ __forceinline__ float dec_f(unsigned u) {
    return (u & 0x80000000u) ? __uint_as_float(u & 0x7FFFFFFFu) : __uint_as_float(~u);
}
__device__ __forceinline__ unsigned long long mkkey(unsigned e, unsigned j) {
    return ((unsigned long long)e << 32) | j;
}
// bf16 round-to-nearest-even of fp32
__device__ __forceinline__ unsigned short bf_hi(float a) {
    unsigned u = __float_as_uint(a);
    unsigned r = u + 0x7FFFu + ((u >> 16) & 1u);
    return (unsigned short)(r >> 16);
}
__device__ __forceinline__ float bf_f(unsigned short h) {
    return __uint_as_float((unsigned)h << 16);
}

// ---------------- fused weight-prep mega-kernel ----------------
__device__ __forceinline__ void wstack_body(const float* __restrict__ w, float* __restrict__ ws,
                                            int O, int Cc, int Kp, int i) {
    if (i >= 2 * O * Kp) return;
    int row = i / Kp, k = i - row * Kp;
    float v = 0.f;
    if (k < Cc) {
        int o = (row < O) ? row : row - O;
        float w1 = w[(size_t)o * 2 * Cc + k];
        v = (row < O) ? w1 : (w[(size_t)o * 2 * Cc + Cc + k] - w1);
    }
    ws[i] = v;
}
__device__ __forceinline__ void wsplit_body(const float* __restrict__ w, int ldin,
                                            unsigned short* __restrict__ h, unsigned short* __restrict__ l,
                                            int Kshift, int i) {
    int row = i >> Kshift, k = i & ((1 << Kshift) - 1);
    float v = w[(size_t)row * ldin + k];
    unsigned short hi = bf_hi(v);
    h[i] = hi;
    l[i] = bf_hi(v - bf_f(hi));
}
// ec4 stacked weight, split directly (rows [0,256)=W1, [256,512)=W2-W1, K=128)
__device__ __forceinline__ void wstacksplit_body(const float* __restrict__ w,
                                                 unsigned short* __restrict__ h, unsigned short* __restrict__ l,
                                                 int i) {
    int row = i >> 7, k = i & 127;
    int o = (row < 256) ? row : row - 256;
    float w1 = w[(size_t)o * 256 + k];
    float v = (row < 256) ? w1 : (w[(size_t)o * 256 + 128 + k] - w1);
    unsigned short hi = bf_hi(v);
    h[i] = hi;
    l[i] = bf_hi(v - bf_f(hi));
}

__global__ void prep_weights_kernel(
        const float* __restrict__ ec1_w, const float* __restrict__ ec2_w,
        const float* __restrict__ ec3_w, const float* __restrict__ ec4_w,
        const float* __restrict__ fuse_w, const float* __restrict__ emb_w,
        const float* __restrict__ h1_w, const float* __restrict__ h2_w,
        float* __restrict__ ws1, float* __restrict__ ws2, float* __restrict__ ws3,
        unsigned short* __restrict__ ws4_h, unsigned short* __restrict__ ws4_l,
        unsigned short* __restrict__ fuse_h, unsigned short* __restrict__ fuse_l,
        unsigned short* __restrict__ emb_h, unsigned short* __restrict__ emb_l,
        unsigned short* __restrict__ h1_h, unsigned short* __restrict__ h1_l,
        unsigned short* __restrict__ h2_h, unsigned short* __restrict__ h2_l,
        unsigned* __restrict__ gmax) {
    int blk = blockIdx.x, tid = threadIdx.x;
    if (blk < 8)            { wstack_body(ec1_w, ws1, 64, 3, 16, blk * 256 + tid); }
    else if (blk < 40)      { wstack_body(ec2_w, ws2, 64, 64, 64, (blk - 8) * 256 + tid); }
    else if (blk < 104)     { wstack_body(ec3_w, ws3, 128, 64, 64, (blk - 40) * 256 + tid); }
    else if (blk < 360)     { wstacksplit_body(ec4_w, ws4_h, ws4_l, (blk - 104) * 256 + tid); }
    else if (blk < 1384)    { wsplit_body(fuse_w, 512, fuse_h, fuse_l, 9, (blk - 360) * 256 + tid); }
    else if (blk < 3432)    { wsplit_body(emb_w, 512, emb_h, emb_l, 9, (blk - 1384) * 256 + tid); }
    else if (blk < 3944)    { wsplit_body(h1_w, 1536, h1_h, h1_l, 9, (blk - 3432) * 256 + tid); }
    else if (blk < 4200)    { wsplit_body(h2_w, 256, h2_h, h2_l, 8, (blk - 3944) * 256 + tid); }
    else                    { int i = (blk - 4200) * 256 + tid;
                              if (i < B_ * 1024) gmax[i] = enc_f(-1e30f); }
}

// xx[m] = ||x_m||^2 ; xt[b][c][n] = x[m][c]
template<int C>
__global__ void prep_kernel(const float* __restrict__ x, int lda,
                            float* __restrict__ xx, float* __restrict__ xt) {
    int m = blockIdx.x * 256 + threadIdx.x;
    if (m >= M_) return;
    int b = m >> 11, n = m & 2047;
    const float* row = x + (size_t)m * lda;
    float s = 0.f;
#pragma unroll 8
    for (int c = 0; c < C; ++c) {
        float v = row[c];
        s = fmaf(v, v, s);
        xt[((size_t)b * C + c) * N_ + n] = v;
    }
    xx[m] = s;
}

// One block (512 thr) = 8 query rows (R10's proven shape). Query-row features
// xi are read as WAVE-UNIFORM scalar loads (s_load -> SGPR operand of fma):
// zero VALU issue cost for the broadcast operand. No per-thread key array
// (spill-proof); acc[8][4] only; enc keys recomputed on demand (bit-identical
// chain). Selection = verified stages A-D. [R12-benched: 135us C=128, VGPR 36]
#define RM 8
template<int C>
__global__ __launch_bounds__(512, 4) void dist_topk_kernel(
        const float* __restrict__ xt, const float* __restrict__ xx,
        int* __restrict__ idxout) {
    __shared__ unsigned m4s[RM][512];             // 16 KB
    __shared__ unsigned long long cand[RM][128];  // 8 KB
    __shared__ int cnt[RM];
    __shared__ unsigned tub[RM];
    int blk = blockIdx.x;
    int b = blk >> 8;
    int i0 = (blk & 255) * RM;
    int tid = threadIdx.x;
    int lane = tid & 63, r = tid >> 6;
    const float* xtb = xt + (size_t)b * C * N_;
    const float* xxb = xx + (size_t)b * N_;

    if (tid < RM) cnt[tid] = 0;
    __syncthreads();

    float xxir[RM];
#pragma unroll
    for (int q = 0; q < RM; ++q) xxir[q] = xxb[i0 + q];   // uniform -> s_load
    float xxj[4];
#pragma unroll
    for (int p = 0; p < 4; ++p) xxj[p] = xxb[tid + 512 * p];

    // ---- compute: 4 cols/thread x 8 rows (fmaf chain ascending in c)
    float acc[RM][4];
#pragma unroll
    for (int q = 0; q < RM; ++q)
#pragma unroll
        for (int p = 0; p < 4; ++p) acc[q][p] = 0.f;

#pragma unroll 4
    for (int c = 0; c < C; ++c) {
        float xtv[4];
#pragma unroll
        for (int p = 0; p < 4; ++p) xtv[p] = xtb[(size_t)c * N_ + tid + 512 * p];
#pragma unroll
        for (int q = 0; q < RM; ++q) {
            float a = xtb[(size_t)c * N_ + i0 + q];       // uniform -> SGPR
#pragma unroll
            for (int p = 0; p < 4; ++p) acc[q][p] = fmaf(a, xtv[p], acc[q][p]);
        }
    }

    // ---- A: per-thread group min (keys recomputed, never stored)
#pragma unroll
    for (int q = 0; q < RM; ++q) {
        unsigned m = 0xFFFFFFFFu;
#pragma unroll
        for (int p = 0; p < 4; ++p) {
            unsigned e = enc_f(xxir[q] + xxj[p] - 2.f * acc[q][p]);
            m = (e < m) ? e : m;
        }
        m4s[q][tid] = m;
    }
    __syncthreads();

    // ---- B: Tub[r] = 20th-smallest lane-min (one live ballot per step)
    {
        unsigned lmin = 0xFFFFFFFFu;
#pragma unroll
        for (int i = 0; i < 8; ++i) {
            unsigned v = m4s[r][lane + 64 * i];
            lmin = (v < lmin) ? v : lmin;
        }
        unsigned T = 0u;
        for (int bpos = 31; bpos >= 0; --bpos) {
            unsigned cd = T | (1u << bpos);
            unsigned long long bal = __ballot(lmin < cd);
            if ((int)__popcll(bal) < KNN) T = cd;
        }
        if (lane == 0) tub[r] = T;
    }
    __syncthreads();

    // ---- C: append candidates (e <= Tub[row]); expected ~24 per row
#pragma unroll
    for (int q = 0; q < RM; ++q) {
        unsigned Tq = tub[q];
#pragma unroll
        for (int p = 0; p < 4; ++p) {
            unsigned e = enc_f(xxir[q] + xxj[p] - 2.f * acc[q][p]);
            if (e <= Tq) {
                int pos = atomicAdd(&cnt[q], 1);
                if (pos < 128)
                    cand[q][pos] = mkkey(e, (unsigned)(tid + 512 * p));
            }
        }
    }
    __syncthreads();

    // ---- D: rank candidates; winners fill slots 0..19 exactly
    int A = cnt[r];
    if (A > 128) A = 128;   // unreachable on continuous data (guarded)
    int* orow = idxout + (size_t)(b * N_ + i0 + r) * KNN;
    for (int cc = lane; cc < A; cc += 64) {
        unsigned long long mykey = cand[r][cc];
        int rank = 0;
        for (int i = 0; i < A; ++i)
            rank += (cand[r][i] < mykey) ? 1 : 0;
        if (rank < KNN) orow[rank] = (int)(mykey & 2047u);
    }
}

// ---------------- MFMA split-bf16 GEMM ----------------
typedef __attribute__((ext_vector_type(8))) short short8;
typedef __attribute__((ext_vector_type(4))) float f32x4;

template<int MODE>
__global__ __launch_bounds__(256, 2) void mgemm_kernel(
        const float* __restrict__ A, int lda,
        const unsigned short* __restrict__ Bh, const unsigned short* __restrict__ Bl, int ldw,
        float* __restrict__ out, int ldo,
        const float* __restrict__ sc, const float* __restrict__ sh,
        const float* __restrict__ addvec, unsigned* __restrict__ gmax,
        int K, int O) {
    __shared__ unsigned short Ah_s[128][40];
    __shared__ unsigned short Al_s[128][40];
    __shared__ unsigned short Bh_s[128][40];
    __shared__ unsigned short Bl_s[128][40];
    int tid = threadIdx.x;
    int lane = tid & 63, w = tid >> 6;
    int ln = lane & 15, kg = lane >> 4;
    int wm = (w >> 1) * 64, wn = (w & 1) * 64;
    int m0 = blockIdx.y * 128, o0 = blockIdx.x * 128;
    f32x4 acc[4][4] = {};

    for (int k0 = 0; k0 < K; k0 += 32) {
#pragma unroll
        for (int j = 0; j < 4; ++j) {
            int s = tid + j * 256;
            int row = s >> 3, q = s & 7;
            float4 v = *(const float4*)&A[(size_t)(m0 + row) * lda + k0 + q * 4];
            unsigned short h0 = bf_hi(v.x), h1 = bf_hi(v.y), h2 = bf_hi(v.z), h3 = bf_hi(v.w);
            unsigned short l0 = bf_hi(v.x - bf_f(h0)), l1 = bf_hi(v.y - bf_f(h1));
            unsigned short l2 = bf_hi(v.z - bf_f(h2)), l3 = bf_hi(v.w - bf_f(h3));
            *(uint2*)&Ah_s[row][q * 4] = make_uint2((unsigned)h0 | ((unsigned)h1 << 16),
                                                    (unsigned)h2 | ((unsigned)h3 << 16));
            *(uint2*)&Al_s[row][q * 4] = make_uint2((unsigned)l0 | ((unsigned)l1 << 16),
                                                    (unsigned)l2 | ((unsigned)l3 << 16));
        }
#pragma unroll
        for (int j = 0; j < 2; ++j) {
            int s = tid + j * 256;
            int row = s >> 2, q = s & 3;
            *(uint4*)&Bh_s[row][q * 8] = *(const uint4*)&Bh[(size_t)(o0 + row) * ldw + k0 + q * 8];
            *(uint4*)&Bl_s[row][q * 8] = *(const uint4*)&Bl[(size_t)(o0 + row) * ldw + k0 + q * 8];
        }
        __syncthreads();

        short8 ah[4], al[4], bh[4], bl[4];
#pragma unroll
        for (int t = 0; t < 4; ++t) {
            ah[t] = *(const short8*)&Ah_s[wm + t * 16 + ln][kg * 8];
            al[t] = *(const short8*)&Al_s[wm + t * 16 + ln][kg * 8];
            bh[t] = *(const short8*)&Bh_s[wn + t * 16 + ln][kg * 8];
            bl[t] = *(const short8*)&Bl_s[wn + t * 16 + ln][kg * 8];
        }
#pragma unroll
        for (int t = 0; t < 4; ++t)
#pragma unroll
            for (int u = 0; u < 4; ++u) {
                acc[t][u] = __builtin_amdgcn_mfma_f32_16x16x32_bf16(ah[t], bh[u], acc[t][u], 0, 0, 0);
                acc[t][u] = __builtin_amdgcn_mfma_f32_16x16x32_bf16(ah[t], bl[u], acc[t][u], 0, 0, 0);
                acc[t][u] = __builtin_amdgcn_mfma_f32_16x16x32_bf16(al[t], bh[u], acc[t][u], 0, 0, 0);
            }
        __syncthreads();
    }

    int b = m0 >> 11;
    if constexpr (MODE == 3) {
#pragma unroll
        for (int u = 0; u < 4; ++u) {
            int o = o0 + wn + u * 16 + ln;
            float s = sc[o], t0 = sh[o];
            float cm = -1e30f;
#pragma unroll
            for (int t = 0; t < 4; ++t)
#pragma unroll
                for (int p = 0; p < 4; ++p) {
                    float v = fmaf(acc[t][u][p], s, t0);
                    v = (v >= 0.f) ? v : NEG * v;
                    cm = fmaxf(cm, v);
                }
            cm = fmaxf(cm, __shfl_xor(cm, 16));
            cm = fmaxf(cm, __shfl_xor(cm, 32));
            if (kg == 0) atomicMax(&gmax[b * 1024 + o], enc_f(cm));
        }
        return;
    }
#pragma unroll
    for (int t = 0; t < 4; ++t)
#pragma unroll
        for (int p = 0; p < 4; ++p) {
            int m = m0 + wm + t * 16 + kg * 4 + p;
#pragma unroll
            for (int u = 0; u < 4; ++u) {
                int o = o0 + wn + u * 16 + ln;
                float v = acc[t][u][p];
                if (MODE == 1) {
                    if (addvec) v += addvec[b * O + o];
                    v = fmaf(v, sc[o], sh[o]);
                    v = (v >= 0.f) ? v : NEG * v;
                }
                out[(size_t)m * ldo + o] = v;
            }
        }
}

// ---------------- fp32 GEMM (ec1..ec3, h3) ----------------
template<int TN, int MODE, bool VEC>
__global__ __launch_bounds__(256, 4) void gemm_kernel(
        const float* __restrict__ A, int lda,
        const float* __restrict__ W, int ldw,
        float* __restrict__ out, int ldo,
        const float* __restrict__ sc, const float* __restrict__ sh,
        const float* __restrict__ addvec, unsigned* __restrict__ gmax,
        int K, int O) {
    constexpr int TM = 128;
    constexpr int JN = TN / 16;
    __shared__ float As[16][TM];
    __shared__ float Bs[16][TN];
    int tid = threadIdx.x;
    int tx = tid & 15, ty = tid >> 4;
    int o0 = blockIdx.x * TN, m0 = blockIdx.y * TM;
    float acc[8][JN] = {};

    for (int k0 = 0; k0 < K; k0 += 16) {
        if constexpr (VEC) {
#pragma unroll
            for (int s = 0; s < 2; ++s) {
                int t = tid + s * 256;
                int row = t >> 2, c4 = (t & 3) << 2;
                float4 v = *(const float4*)&A[(size_t)(m0 + row) * lda + k0 + c4];
                As[c4 + 0][row] = v.x; As[c4 + 1][row] = v.y;
                As[c4 + 2][row] = v.z; As[c4 + 3][row] = v.w;
            }
#pragma unroll
            for (int s = 0; s < TN / 64; ++s) {
                int t = tid + s * 256;
                int row = t >> 2, c4 = (t & 3) << 2;
                int o = o0 + row;
                float4 v = make_float4(0.f, 0.f, 0.f, 0.f);
                if (o < O) v = *(const float4*)&W[(size_t)o * ldw + k0 + c4];
                Bs[c4 + 0][row] = v.x; Bs[c4 + 1][row] = v.y;
                Bs[c4 + 2][row] = v.z; Bs[c4 + 3][row] = v.w;
            }
        } else {
            for (int t = tid; t < TM * 16; t += 256) {
                int row = t >> 4, k = t & 15;
                As[k][row] = (k0 + k < K) ? A[(size_t)(m0 + row) * lda + k0 + k] : 0.f;
            }
            for (int t = tid; t < TN * 16; t += 256) {
                int row = t >> 4, k = t & 15;
                Bs[k][row] = W[(size_t)(o0 + row) * ldw + k0 + k];
            }
        }
        __syncthreads();
#pragma unroll
        for (int kk = 0; kk < 16; ++kk) {
            float a[8], bv[JN];
            *(float4*)&a[0] = *(const float4*)&As[kk][ty * 8];
            *(float4*)&a[4] = *(const float4*)&As[kk][ty * 8 + 4];
            *(float4*)&bv[0] = *(const float4*)&Bs[kk][tx * JN];
            if (JN == 8) *(float4*)&bv[4] = *(const float4*)&Bs[kk][tx * JN + 4];
#pragma unroll
            for (int i = 0; i < 8; ++i)
#pragma unroll
                for (int j = 0; j < JN; ++j)
                    acc[i][j] = fmaf(a[i], bv[j], acc[i][j]);
        }
        __syncthreads();
    }

    int b = m0 >> 11;
    bool fullstore = (o0 + TN <= O) && ((ldo & 3) == 0);
#pragma unroll
    for (int i = 0; i < 8; ++i) {
        int m = m0 + ty * 8 + i;
        float vals[JN];
#pragma unroll
        for (int j = 0; j < JN; ++j) {
            int o = o0 + tx * JN + j;
            float v = acc[i][j];
            if (MODE == 1) {
                if (addvec) v += addvec[b * O + o];
                v = fmaf(v, sc[o], sh[o]);
                v = (v >= 0.f) ? v : NEG * v;
            } else if (MODE == 2) {
                v += sh[o];
            }
            vals[j] = v;
        }
        if (fullstore) {
#pragma unroll
            for (int j0 = 0; j0 < JN; j0 += 4)
                *(float4*)&out[(size_t)m * ldo + o0 + tx * JN + j0] = *(float4*)&vals[j0];
        } else {
#pragma unroll
            for (int j = 0; j < JN; ++j) {
                int o = o0 + tx * JN + j;
                if (o < O) out[(size_t)m * ldo + o] = vals[j];
            }
        }
    }
}

// out[m][o..o+3] = max_k lrelu((y[nbr_k] + z[m]) * sc + sh); y/z packed in yz.
__global__ void edge_max_kernel(const float* __restrict__ yz, const int* __restrict__ idx,
                                const float* __restrict__ sc, const float* __restrict__ sh,
                                float* __restrict__ out, int ldo, int oshift) {
    int gid = blockIdx.x * 256 + threadIdx.x;
    int O = 1 << oshift;
    int m = gid >> (oshift - 2);
    int o = (gid & ((1 << (oshift - 2)) - 1)) << 2;
    int ldyz = 2 * O;
    float4 z = *(const float4*)&yz[(size_t)m * ldyz + O + o];
    float4 s4 = *(const float4*)&sc[o];
    float4 t4 = *(const float4*)&sh[o];
    const int* ip = idx + (size_t)m * KNN;
    int bbase = m & ~(N_ - 1);
    float4 mv = make_float4(-1e30f, -1e30f, -1e30f, -1e30f);
#pragma unroll
    for (int kk = 0; kk < KNN; ++kk) {
        int j = ip[kk];
        float4 y = *(const float4*)&yz[(size_t)(bbase + j) * ldyz + o];
        float v;
        v = fmaf(y.x + z.x, s4.x, t4.x); v = (v >= 0.f) ? v : NEG * v; mv.x = fmaxf(mv.x, v);
        v = fmaf(y.y + z.y, s4.y, t4.y); v = (v >= 0.f) ? v : NEG * v; mv.y = fmaxf(mv.y, v);
        v = fmaf(y.z + z.z, s4.z, t4.z); v = (v >= 0.f) ? v : NEG * v; mv.z = fmaxf(mv.z, v);
        v = fmaf(y.w + z.w, s4.w, t4.w); v = (v >= 0.f) ? v : NEG * v; mv.w = fmaxf(mv.w, v);
    }
    *(float4*)&out[(size_t)m * ldo + o] = mv;
}

// corr[b][o] = sum_c dec(gmax[b][c]) * h1w[o][512+c]   (decode folded in)
__global__ void corr_kernel(const unsigned* __restrict__ gmax, const float* __restrict__ h1w,
                            float* __restrict__ corr) {
    int wid = (blockIdx.x * 256 + threadIdx.x) >> 6;
    int lane = threadIdx.x & 63;
    int b = wid >> 8, o = wid & 255;
    const unsigned* g = gmax + b * 1024;
    const float* w = h1w + (size_t)o * 1536 + 512;
    float s = 0.f;
    for (int c = lane; c < 1024; c += 64) s = fmaf(dec_f(g[c]), w[c], s);
#pragma unroll
    for (int off = 32; off >= 1; off >>= 1) s += __shfl_xor(s, off);
    if (lane == 0) corr[b * 256 + o] = s;
}

extern "C" void kernel_launch(void* const* d_in, const int* in_sizes, int n_in,
                              void* d_out, int out_size, void* d_ws, size_t ws_size,
                              hipStream_t stream) {
    const float* xyz    = (const float*)d_in[0];
    const float* ec1_w  = (const float*)d_in[1];
    const float* ec1_s  = (const float*)d_in[2];
    const float* ec1_t  = (const float*)d_in[3];
    const float* ec2_w  = (const float*)d_in[4];
    const float* ec2_s  = (const float*)d_in[5];
    const float* ec2_t  = (const float*)d_in[6];
    const float* ec3_w  = (const float*)d_in[7];
    const float* ec3_s  = (const float*)d_in[8];
    const float* ec3_t  = (const float*)d_in[9];
    const float* ec4_w  = (const float*)d_in[10];
    const float* ec4_s  = (const float*)d_in[11];
    const float* ec4_t  = (const float*)d_in[12];
    const float* fuse_w = (const float*)d_in[13];
    const float* fuse_s = (const float*)d_in[14];
    const float* fuse_t = (const float*)d_in[15];
    const float* emb_w  = (const float*)d_in[16];
    const float* emb_s  = (const float*)d_in[17];
    const float* emb_t  = (const float*)d_in[18];
    const float* h1_w   = (const float*)d_in[19];
    const float* h1_s   = (const float*)d_in[20];
    const float* h1_t   = (const float*)d_in[21];
    const float* h2_w   = (const float*)d_in[22];
    const float* h2_s   = (const float*)d_in[23];
    const float* h2_t   = (const float*)d_in[24];
    const float* h3_w   = (const float*)d_in[25];
    const float* h3_b   = (const float*)d_in[26];
    float* out = (float*)d_out;

    float* ws = (float*)d_ws;
    size_t off = 0;
    float* xcat = ws + off; off += (size_t)M_ * 512;
    float* xloc = ws + off; off += (size_t)M_ * 512;
    float* yz   = ws + off; off += (size_t)M_ * 512;
    float* xt   = ws + off; off += (size_t)B_ * 128 * N_;
    float* xx   = ws + off; off += M_;
    int*   idx  = (int*)(ws + off); off += (size_t)M_ * KNN;
    float* ws1  = ws + off; off += 2 * 64 * 16;
    float* ws2  = ws + off; off += 2 * 64 * 64;
    float* ws3  = ws + off; off += 2 * 128 * 64;
    unsigned* gmax = (unsigned*)(ws + off); off += B_ * 1024;
    float* corr = ws + off; off += B_ * 256;
    unsigned short* fuse_h = (unsigned short*)(ws + off); off += 512 * 512 / 2;
    unsigned short* fuse_l = (unsigned short*)(ws + off); off += 512 * 512 / 2;
    unsigned short* emb_h  = (unsigned short*)(ws + off); off += 1024 * 512 / 2;
    unsigned short* emb_l  = (unsigned short*)(ws + off); off += 1024 * 512 / 2;
    unsigned short* h1_h   = (unsigned short*)(ws + off); off += 256 * 512 / 2;
    unsigned short* h1_l   = (unsigned short*)(ws + off); off += 256 * 512 / 2;
    unsigned short* h2_h   = (unsigned short*)(ws + off); off += 256 * 256 / 2;
    unsigned short* h2_l   = (unsigned short*)(ws + off); off += 256 * 256 / 2;
    unsigned short* ws4_h  = (unsigned short*)(ws + off); off += 512 * 128 / 2;
    unsigned short* ws4_l  = (unsigned short*)(ws + off); off += 512 * 128 / 2;
    float* h1o  = yz;                       // reuse after ec4's edge_max
    float* h2o  = yz + (size_t)M_ * 256;

    // ---- all weight prep + gmax init in ONE launch
    prep_weights_kernel<<<4232, 256, 0, stream>>>(
        ec1_w, ec2_w, ec3_w, ec4_w, fuse_w, emb_w, h1_w, h2_w,
        ws1, ws2, ws3, ws4_h, ws4_l, fuse_h, fuse_l, emb_h, emb_l,
        h1_h, h1_l, h2_h, h2_l, gmax);

    // ---- EdgeConv 1: xyz (C=3) -> xcat[:, 0:64]   (fp32 path, exact)
    prep_kernel<3><<<M_ / 256, 256, 0, stream>>>(xyz, 3, xx, xt);
    dist_topk_kernel<3><<<M_ / RM, 512, 0, stream>>>(xt, xx, idx);
    gemm_kernel<128, 0, false><<<dim3(1, M_ / 128), 256, 0, stream>>>(xyz, 3, ws1, 16, yz, 128, nullptr, nullptr, nullptr, nullptr, 3, 128);
    edge_max_kernel<<<(M_ * 16) / 256, 256, 0, stream>>>(yz, idx, ec1_s, ec1_t, xcat + 0, 512, 6);

    // ---- EdgeConv 2
    prep_kernel<64><<<M_ / 256, 256, 0, stream>>>(xcat + 0, 512, xx, xt);
    dist_topk_kernel<64><<<M_ / RM, 512, 0, stream>>>(xt, xx, idx);
    gemm_kernel<64, 0, true><<<dim3(2, M_ / 128), 256, 0, stream>>>(xcat + 0, 512, ws2, 64, yz, 128, nullptr, nullptr, nullptr, nullptr, 64, 128);
    edge_max_kernel<<<(M_ * 16) / 256, 256, 0, stream>>>(yz, idx, ec2_s, ec2_t, xcat + 64, 512, 6);

    // ---- EdgeConv 3
    prep_kernel<64><<<M_ / 256, 256, 0, stream>>>(xcat + 64, 512, xx, xt);
    dist_topk_kernel<64><<<M_ / RM, 512, 0, stream>>>(xt, xx, idx);
    gemm_kernel<128, 0, true><<<dim3(2, M_ / 128), 256, 0, stream>>>(xcat + 64, 512, ws3, 64, yz, 256, nullptr, nullptr, nullptr, nullptr, 64, 256);
    edge_max_kernel<<<(M_ * 32) / 256, 256, 0, stream>>>(yz, idx, ec3_s, ec3_t, xcat + 128, 512, 7);

    // ---- EdgeConv 4 (gemm output feeds no KNN -> MFMA-safe)
    prep_kernel<128><<<M_ / 256, 256, 0, stream>>>(xcat + 128, 512, xx, xt);
    dist_topk_kernel<128><<<M_ / RM, 512, 0, stream>>>(xt, xx, idx);
    mgemm_kernel<0><<<dim3(4, M_ / 128), 256, 0, stream>>>(xcat + 128, 512, ws4_h, ws4_l, 128, yz, 512, nullptr, nullptr, nullptr, nullptr, 128, 512);
    edge_max_kernel<<<(M_ * 64) / 256, 256, 0, stream>>>(yz, idx, ec4_s, ec4_t, xcat + 256, 512, 8);

    // ---- fuse: xcat(512) -> x_local(512), lrelu  [MFMA split-bf16]
    mgemm_kernel<1><<<dim3(4, M_ / 128), 256, 0, stream>>>(xcat, 512, fuse_h, fuse_l, 512, xloc, 512, fuse_s, fuse_t, nullptr, nullptr, 512, 512);

    // ---- emb: x_local -> (max over N) gmax  [MFMA split-bf16 + atomicMax]
    mgemm_kernel<3><<<dim3(8, M_ / 128), 256, 0, stream>>>(xloc, 512, emb_h, emb_l, 512, nullptr, 0, emb_s, emb_t, nullptr, gmax, 512, 1024);
    corr_kernel<<<512, 256, 0, stream>>>(gmax, h1_w, corr);

    // ---- h1: [x_local | glob] -> 256 ; glob part via corr  [MFMA]
    mgemm_kernel<1><<<dim3(2, M_ / 128), 256, 0, stream>>>(xloc, 512, h1_h, h1_l, 512, h1o, 256, h1_s, h1_t, corr, nullptr, 512, 256);
    // ---- h2: 256 -> 256  [MFMA]
    mgemm_kernel<1><<<dim3(2, M_ / 128), 256, 0, stream>>>(h1o, 256, h2_h, h2_l, 256, h2o, 256, h2_s, h2_t, nullptr, nullptr, 256, 256);
    // ---- h3: 256 -> 13 (+bias)  [fp32]
    gemm_kernel<64, 2, true><<<dim3(1, M_ / 128), 256, 0, stream>>>(h2o, 256, h3_w, 256, out, 13, nullptr, h3_b, nullptr, nullptr, 256, 13);
}

// Round 15
// 699.687 us; speedup vs baseline: 1.1547x; 1.0622x over previous
//
#include <hip/hip_runtime.h>

#define B_  8
#define N_  2048
#define M_  16384
#define KNN 20
#define NEG 0.2f

__device__ __forceinline__ unsigned enc_f(float f) {
    unsigned u = __float_as_uint(f);
    return (u & 0x80000000u) ? ~u : (u | 0x80000000u);
}
__device__ __forceinline__ float dec_f(unsigned u) {
    return (u & 0x80000000u) ? __uint_as_float(u & 0x7FFFFFFFu) : __uint_as_float(~u);
}
__device__ __forceinline__ unsigned long long mkkey(unsigned e, unsigned j) {
    return ((unsigned long long)e << 32) | j;
}
// bf16 round-to-nearest-even of fp32
__device__ __forceinline__ unsigned short bf_hi(float a) {
    unsigned u = __float_as_uint(a);
    unsigned r = u + 0x7FFFu + ((u >> 16) & 1u);
    return (unsigned short)(r >> 16);
}
__device__ __forceinline__ float bf_f(unsigned short h) {
    return __uint_as_float((unsigned)h << 16);
}

// ---------------- fused weight-prep mega-kernel ----------------
__device__ __forceinline__ void wstack_body(const float* __restrict__ w, float* __restrict__ ws,
                                            int O, int Cc, int Kp, int i) {
    if (i >= 2 * O * Kp) return;
    int row = i / Kp, k = i - row * Kp;
    float v = 0.f;
    if (k < Cc) {
        int o = (row < O) ? row : row - O;
        float w1 = w[(size_t)o * 2 * Cc + k];
        v = (row < O) ? w1 : (w[(size_t)o * 2 * Cc + Cc + k] - w1);
    }
    ws[i] = v;
}
__device__ __forceinline__ void wsplit_body(const float* __restrict__ w, int ldin,
                                            unsigned short* __restrict__ h, unsigned short* __restrict__ l,
                                            int Kshift, int i) {
    int row = i >> Kshift, k = i & ((1 << Kshift) - 1);
    float v = w[(size_t)row * ldin + k];
    unsigned short hi = bf_hi(v);
    h[i] = hi;
    l[i] = bf_hi(v - bf_f(hi));
}
// ec4 stacked weight, split directly (rows [0,256)=W1, [256,512)=W2-W1, K=128)
__device__ __forceinline__ void wstacksplit_body(const float* __restrict__ w,
                                                 unsigned short* __restrict__ h, unsigned short* __restrict__ l,
                                                 int i) {
    int row = i >> 7, k = i & 127;
    int o = (row < 256) ? row : row - 256;
    float w1 = w[(size_t)o * 256 + k];
    float v = (row < 256) ? w1 : (w[(size_t)o * 256 + 128 + k] - w1);
    unsigned short hi = bf_hi(v);
    h[i] = hi;
    l[i] = bf_hi(v - bf_f(hi));
}

__global__ void prep_weights_kernel(
        const float* __restrict__ ec1_w, const float* __restrict__ ec2_w,
        const float* __restrict__ ec3_w, const float* __restrict__ ec4_w,
        const float* __restrict__ fuse_w, const float* __restrict__ emb_w,
        const float* __restrict__ h1_w, const float* __restrict__ h2_w,
        float* __restrict__ ws1, float* __restrict__ ws2, float* __restrict__ ws3,
        unsigned short* __restrict__ ws4_h, unsigned short* __restrict__ ws4_l,
        unsigned short* __restrict__ fuse_h, unsigned short* __restrict__ fuse_l,
        unsigned short* __restrict__ emb_h, unsigned short* __restrict__ emb_l,
        unsigned short* __restrict__ h1_h, unsigned short* __restrict__ h1_l,
        unsigned short* __restrict__ h2_h, unsigned short* __restrict__ h2_l,
        unsigned* __restrict__ gmax) {
    int blk = blockIdx.x, tid = threadIdx.x;
    if (blk < 8)            { wstack_body(ec1_w, ws1, 64, 3, 16, blk * 256 + tid); }
    else if (blk < 40)      { wstack_body(ec2_w, ws2, 64, 64, 64, (blk - 8) * 256 + tid); }
    else if (blk < 104)     { wstack_body(ec3_w, ws3, 128, 64, 64, (blk - 40) * 256 + tid); }
    else if (blk < 360)     { wstacksplit_body(ec4_w, ws4_h, ws4_l, (blk - 104) * 256 + tid); }
    else if (blk < 1384)    { wsplit_body(fuse_w, 512, fuse_h, fuse_l, 9, (blk - 360) * 256 + tid); }
    else if (blk < 3432)    { wsplit_body(emb_w, 512, emb_h, emb_l, 9, (blk - 1384) * 256 + tid); }
    else if (blk < 3944)    { wsplit_body(h1_w, 1536, h1_h, h1_l, 9, (blk - 3432) * 256 + tid); }
    else if (blk < 4200)    { wsplit_body(h2_w, 256, h2_h, h2_l, 8, (blk - 3944) * 256 + tid); }
    else                    { int i = (blk - 4200) * 256 + tid;
                              if (i < B_ * 1024) gmax[i] = enc_f(-1e30f); }
}

// xx[m] = ||x_m||^2 ; xt[b][c][n] = x[m][c]
template<int C>
__global__ void prep_kernel(const float* __restrict__ x, int lda,
                            float* __restrict__ xx, float* __restrict__ xt) {
    int m = blockIdx.x * 256 + threadIdx.x;
    if (m >= M_) return;
    int b = m >> 11, n = m & 2047;
    const float* row = x + (size_t)m * lda;
    float s = 0.f;
#pragma unroll 8
    for (int c = 0; c < C; ++c) {
        float v = row[c];
        s = fmaf(v, v, s);
        xt[((size_t)b * C + c) * N_ + n] = v;
    }
    xx[m] = s;
}

// One block (512 thr) = 8 query rows; xi via wave-uniform scalar loads.
// No per-thread key array (spill-proof); acc[8][4] only; enc keys recomputed
// on demand (bit-identical chain). Selection = verified stages A-D.
// [R12/R14-benched: ~134us C=128, VGPR 36, no spill]
#define RM 8
template<int C>
__global__ __launch_bounds__(512, 4) void dist_topk_kernel(
        const float* __restrict__ xt, const float* __restrict__ xx,
        int* __restrict__ idxout) {
    __shared__ unsigned m4s[RM][512];             // 16 KB
    __shared__ unsigned long long cand[RM][128];  // 8 KB
    __shared__ int cnt[RM];
    __shared__ unsigned tub[RM];
    int blk = blockIdx.x;
    int b = blk >> 8;
    int i0 = (blk & 255) * RM;
    int tid = threadIdx.x;
    int lane = tid & 63, r = tid >> 6;
    const float* xtb = xt + (size_t)b * C * N_;
    const float* xxb = xx + (size_t)b * N_;

    if (tid < RM) cnt[tid] = 0;
    __syncthreads();

    float xxir[RM];
#pragma unroll
    for (int q = 0; q < RM; ++q) xxir[q] = xxb[i0 + q];   // uniform -> s_load
    float xxj[4];
#pragma unroll
    for (int p = 0; p < 4; ++p) xxj[p] = xxb[tid + 512 * p];

    // ---- compute: 4 cols/thread x 8 rows (fmaf chain ascending in c)
    float acc[RM][4];
#pragma unroll
    for (int q = 0; q < RM; ++q)
#pragma unroll
        for (int p = 0; p < 4; ++p) acc[q][p] = 0.f;

#pragma unroll 4
    for (int c = 0; c < C; ++c) {
        float xtv[4];
#pragma unroll
        for (int p = 0; p < 4; ++p) xtv[p] = xtb[(size_t)c * N_ + tid + 512 * p];
#pragma unroll
        for (int q = 0; q < RM; ++q) {
            float a = xtb[(size_t)c * N_ + i0 + q];       // uniform -> SGPR
#pragma unroll
            for (int p = 0; p < 4; ++p) acc[q][p] = fmaf(a, xtv[p], acc[q][p]);
        }
    }

    // ---- A: per-thread group min (keys recomputed, never stored)
#pragma unroll
    for (int q = 0; q < RM; ++q) {
        unsigned m = 0xFFFFFFFFu;
#pragma unroll
        for (int p = 0; p < 4; ++p) {
            unsigned e = enc_f(xxir[q] + xxj[p] - 2.f * acc[q][p]);
            m = (e < m) ? e : m;
        }
        m4s[q][tid] = m;
    }
    __syncthreads();

    // ---- B: Tub[r] = 20th-smallest lane-min (one live ballot per step)
    {
        unsigned lmin = 0xFFFFFFFFu;
#pragma unroll
        for (int i = 0; i < 8; ++i) {
            unsigned v = m4s[r][lane + 64 * i];
            lmin = (v < lmin) ? v : lmin;
        }
        unsigned T = 0u;
        for (int bpos = 31; bpos >= 0; --bpos) {
            unsigned cd = T | (1u << bpos);
            unsigned long long bal = __ballot(lmin < cd);
            if ((int)__popcll(bal) < KNN) T = cd;
        }
        if (lane == 0) tub[r] = T;
    }
    __syncthreads();

    // ---- C: append candidates (e <= Tub[row]); expected ~24 per row
#pragma unroll
    for (int q = 0; q < RM; ++q) {
        unsigned Tq = tub[q];
#pragma unroll
        for (int p = 0; p < 4; ++p) {
            unsigned e = enc_f(xxir[q] + xxj[p] - 2.f * acc[q][p]);
            if (e <= Tq) {
                int pos = atomicAdd(&cnt[q], 1);
                if (pos < 128)
                    cand[q][pos] = mkkey(e, (unsigned)(tid + 512 * p));
            }
        }
    }
    __syncthreads();

    // ---- D: rank candidates; winners fill slots 0..19 exactly
    int A = cnt[r];
    if (A > 128) A = 128;   // unreachable on continuous data (guarded)
    int* orow = idxout + (size_t)(b * N_ + i0 + r) * KNN;
    for (int cc = lane; cc < A; cc += 64) {
        unsigned long long mykey = cand[r][cc];
        int rank = 0;
        for (int i = 0; i < A; ++i)
            rank += (cand[r][i] < mykey) ? 1 : 0;
        if (rank < KNN) orow[rank] = (int)(mykey & 2047u);
    }
}

// ---------------- MFMA split-bf16 GEMM ----------------
// Occupancy 2 -> 3 blocks/CU (12 waves/CU): more wave-level overlap to hide
// staging latency in the barrier-bound K-loop. LDS 40 KB x 3 = 120 <= 160 KB;
// VGPR est ~155 < 168 cap. Spill tripwire: mgemm WRITE_SIZE blowup.
typedef __attribute__((ext_vector_type(8))) short short8;
typedef __attribute__((ext_vector_type(4))) float f32x4;

template<int MODE>
__global__ __launch_bounds__(256, 3) void mgemm_kernel(
        const float* __restrict__ A, int lda,
        const unsigned short* __restrict__ Bh, const unsigned short* __restrict__ Bl, int ldw,
        float* __restrict__ out, int ldo,
        const float* __restrict__ sc, const float* __restrict__ sh,
        const float* __restrict__ addvec, unsigned* __restrict__ gmax,
        int K, int O) {
    __shared__ unsigned short Ah_s[128][40];
    __shared__ unsigned short Al_s[128][40];
    __shared__ unsigned short Bh_s[128][40];
    __shared__ unsigned short Bl_s[128][40];
    int tid = threadIdx.x;
    int lane = tid & 63, w = tid >> 6;
    int ln = lane & 15, kg = lane >> 4;
    int wm = (w >> 1) * 64, wn = (w & 1) * 64;
    int m0 = blockIdx.y * 128, o0 = blockIdx.x * 128;
    f32x4 acc[4][4] = {};

    for (int k0 = 0; k0 < K; k0 += 32) {
#pragma unroll
        for (int j = 0; j < 4; ++j) {
            int s = tid + j * 256;
            int row = s >> 3, q = s & 7;
            float4 v = *(const float4*)&A[(size_t)(m0 + row) * lda + k0 + q * 4];
            unsigned short h0 = bf_hi(v.x), h1 = bf_hi(v.y), h2 = bf_hi(v.z), h3 = bf_hi(v.w);
            unsigned short l0 = bf_hi(v.x - bf_f(h0)), l1 = bf_hi(v.y - bf_f(h1));
            unsigned short l2 = bf_hi(v.z - bf_f(h2)), l3 = bf_hi(v.w - bf_f(h3));
            *(uint2*)&Ah_s[row][q * 4] = make_uint2((unsigned)h0 | ((unsigned)h1 << 16),
                                                    (unsigned)h2 | ((unsigned)h3 << 16));
            *(uint2*)&Al_s[row][q * 4] = make_uint2((unsigned)l0 | ((unsigned)l1 << 16),
                                                    (unsigned)l2 | ((unsigned)l3 << 16));
        }
#pragma unroll
        for (int j = 0; j < 2; ++j) {
            int s = tid + j * 256;
            int row = s >> 2, q = s & 3;
            *(uint4*)&Bh_s[row][q * 8] = *(const uint4*)&Bh[(size_t)(o0 + row) * ldw + k0 + q * 8];
            *(uint4*)&Bl_s[row][q * 8] = *(const uint4*)&Bl[(size_t)(o0 + row) * ldw + k0 + q * 8];
        }
        __syncthreads();

        short8 ah[4], al[4], bh[4], bl[4];
#pragma unroll
        for (int t = 0; t < 4; ++t) {
            ah[t] = *(const short8*)&Ah_s[wm + t * 16 + ln][kg * 8];
            al[t] = *(const short8*)&Al_s[wm + t * 16 + ln][kg * 8];
            bh[t] = *(const short8*)&Bh_s[wn + t * 16 + ln][kg * 8];
            bl[t] = *(const short8*)&Bl_s[wn + t * 16 + ln][kg * 8];
        }
#pragma unroll
        for (int t = 0; t < 4; ++t)
#pragma unroll
            for (int u = 0; u < 4; ++u) {
                acc[t][u] = __builtin_amdgcn_mfma_f32_16x16x32_bf16(ah[t], bh[u], acc[t][u], 0, 0, 0);
                acc[t][u] = __builtin_amdgcn_mfma_f32_16x16x32_bf16(ah[t], bl[u], acc[t][u], 0, 0, 0);
                acc[t][u] = __builtin_amdgcn_mfma_f32_16x16x32_bf16(al[t], bh[u], acc[t][u], 0, 0, 0);
            }
        __syncthreads();
    }

    int b = m0 >> 11;
    if constexpr (MODE == 3) {
#pragma unroll
        for (int u = 0; u < 4; ++u) {
            int o = o0 + wn + u * 16 + ln;
            float s = sc[o], t0 = sh[o];
            float cm = -1e30f;
#pragma unroll
            for (int t = 0; t < 4; ++t)
#pragma unroll
                for (int p = 0; p < 4; ++p) {
                    float v = fmaf(acc[t][u][p], s, t0);
                    v = (v >= 0.f) ? v : NEG * v;
                    cm = fmaxf(cm, v);
                }
            cm = fmaxf(cm, __shfl_xor(cm, 16));
            cm = fmaxf(cm, __shfl_xor(cm, 32));
            if (kg == 0) atomicMax(&gmax[b * 1024 + o], enc_f(cm));
        }
        return;
    }
#pragma unroll
    for (int t = 0; t < 4; ++t)
#pragma unroll
        for (int p = 0; p < 4; ++p) {
            int m = m0 + wm + t * 16 + kg * 4 + p;
#pragma unroll
            for (int u = 0; u < 4; ++u) {
                int o = o0 + wn + u * 16 + ln;
                float v = acc[t][u][p];
                if (MODE == 1) {
                    if (addvec) v += addvec[b * O + o];
                    v = fmaf(v, sc[o], sh[o]);
                    v = (v >= 0.f) ? v : NEG * v;
                }
                out[(size_t)m * ldo + o] = v;
            }
        }
}

// ---------------- fp32 GEMM (ec1..ec3, h3) ----------------
template<int TN, int MODE, bool VEC>
__global__ __launch_bounds__(256, 4) void gemm_kernel(
        const float* __restrict__ A, int lda,
        const float* __restrict__ W, int ldw,
        float* __restrict__ out, int ldo,
        const float* __restrict__ sc, const float* __restrict__ sh,
        const float* __restrict__ addvec, unsigned* __restrict__ gmax,
        int K, int O) {
    constexpr int TM = 128;
    constexpr int JN = TN / 16;
    __shared__ float As[16][TM];
    __shared__ float Bs[16][TN];
    int tid = threadIdx.x;
    int tx = tid & 15, ty = tid >> 4;
    int o0 = blockIdx.x * TN, m0 = blockIdx.y * TM;
    float acc[8][JN] = {};

    for (int k0 = 0; k0 < K; k0 += 16) {
        if constexpr (VEC) {
#pragma unroll
            for (int s = 0; s < 2; ++s) {
                int t = tid + s * 256;
                int row = t >> 2, c4 = (t & 3) << 2;
                float4 v = *(const float4*)&A[(size_t)(m0 + row) * lda + k0 + c4];
                As[c4 + 0][row] = v.x; As[c4 + 1][row] = v.y;
                As[c4 + 2][row] = v.z; As[c4 + 3][row] = v.w;
            }
#pragma unroll
            for (int s = 0; s < TN / 64; ++s) {
                int t = tid + s * 256;
                int row = t >> 2, c4 = (t & 3) << 2;
                int o = o0 + row;
                float4 v = make_float4(0.f, 0.f, 0.f, 0.f);
                if (o < O) v = *(const float4*)&W[(size_t)o * ldw + k0 + c4];
                Bs[c4 + 0][row] = v.x; Bs[c4 + 1][row] = v.y;
                Bs[c4 + 2][row] = v.z; Bs[c4 + 3][row] = v.w;
            }
        } else {
            for (int t = tid; t < TM * 16; t += 256) {
                int row = t >> 4, k = t & 15;
                As[k][row] = (k0 + k < K) ? A[(size_t)(m0 + row) * lda + k0 + k] : 0.f;
            }
            for (int t = tid; t < TN * 16; t += 256) {
                int row = t >> 4, k = t & 15;
                Bs[k][row] = W[(size_t)(o0 + row) * ldw + k0 + k];
            }
        }
        __syncthreads();
#pragma unroll
        for (int kk = 0; kk < 16; ++kk) {
            float a[8], bv[JN];
            *(float4*)&a[0] = *(const float4*)&As[kk][ty * 8];
            *(float4*)&a[4] = *(const float4*)&As[kk][ty * 8 + 4];
            *(float4*)&bv[0] = *(const float4*)&Bs[kk][tx * JN];
            if (JN == 8) *(float4*)&bv[4] = *(const float4*)&Bs[kk][tx * JN + 4];
#pragma unroll
            for (int i = 0; i < 8; ++i)
#pragma unroll
                for (int j = 0; j < JN; ++j)
                    acc[i][j] = fmaf(a[i], bv[j], acc[i][j]);
        }
        __syncthreads();
    }

    int b = m0 >> 11;
    bool fullstore = (o0 + TN <= O) && ((ldo & 3) == 0);
#pragma unroll
    for (int i = 0; i < 8; ++i) {
        int m = m0 + ty * 8 + i;
        float vals[JN];
#pragma unroll
        for (int j = 0; j < JN; ++j) {
            int o = o0 + tx * JN + j;
            float v = acc[i][j];
            if (MODE == 1) {
                if (addvec) v += addvec[b * O + o];
                v = fmaf(v, sc[o], sh[o]);
                v = (v >= 0.f) ? v : NEG * v;
            } else if (MODE == 2) {
                v += sh[o];
            }
            vals[j] = v;
        }
        if (fullstore) {
#pragma unroll
            for (int j0 = 0; j0 < JN; j0 += 4)
                *(float4*)&out[(size_t)m * ldo + o0 + tx * JN + j0] = *(float4*)&vals[j0];
        } else {
#pragma unroll
            for (int j = 0; j < JN; ++j) {
                int o = o0 + tx * JN + j;
                if (o < O) out[(size_t)m * ldo + o] = vals[j];
            }
        }
    }
}

// out[m][o..o+3] = max_k lrelu((y[nbr_k] + z[m]) * sc + sh); y/z packed in yz.
__global__ void edge_max_kernel(const float* __restrict__ yz, const int* __restrict__ idx,
                                const float* __restrict__ sc, const float* __restrict__ sh,
                                float* __restrict__ out, int ldo, int oshift) {
    int gid = blockIdx.x * 256 + threadIdx.x;
    int O = 1 << oshift;
    int m = gid >> (oshift - 2);
    int o = (gid & ((1 << (oshift - 2)) - 1)) << 2;
    int ldyz = 2 * O;
    float4 z = *(const float4*)&yz[(size_t)m * ldyz + O + o];
    float4 s4 = *(const float4*)&sc[o];
    float4 t4 = *(const float4*)&sh[o];
    const int* ip = idx + (size_t)m * KNN;
    int bbase = m & ~(N_ - 1);
    float4 mv = make_float4(-1e30f, -1e30f, -1e30f, -1e30f);
#pragma unroll
    for (int kk = 0; kk < KNN; ++kk) {
        int j = ip[kk];
        float4 y = *(const float4*)&yz[(size_t)(bbase + j) * ldyz + o];
        float v;
        v = fmaf(y.x + z.x, s4.x, t4.x); v = (v >= 0.f) ? v : NEG * v; mv.x = fmaxf(mv.x, v);
        v = fmaf(y.y + z.y, s4.y, t4.y); v = (v >= 0.f) ? v : NEG * v; mv.y = fmaxf(mv.y, v);
        v = fmaf(y.z + z.z, s4.z, t4.z); v = (v >= 0.f) ? v : NEG * v; mv.z = fmaxf(mv.z, v);
        v = fmaf(y.w + z.w, s4.w, t4.w); v = (v >= 0.f) ? v : NEG * v; mv.w = fmaxf(mv.w, v);
    }
    *(float4*)&out[(size_t)m * ldo + o] = mv;
}

// corr[b][o] = sum_c dec(gmax[b][c]) * h1w[o][512+c]   (decode folded in)
__global__ void corr_kernel(const unsigned* __restrict__ gmax, const float* __restrict__ h1w,
                            float* __restrict__ corr) {
    int wid = (blockIdx.x * 256 + threadIdx.x) >> 6;
    int lane = threadIdx.x & 63;
    int b = wid >> 8, o = wid & 255;
    const unsigned* g = gmax + b * 1024;
    const float* w = h1w + (size_t)o * 1536 + 512;
    float s = 0.f;
    for (int c = lane; c < 1024; c += 64) s = fmaf(dec_f(g[c]), w[c], s);
#pragma unroll
    for (int off = 32; off >= 1; off >>= 1) s += __shfl_xor(s, off);
    if (lane == 0) corr[b * 256 + o] = s;
}

extern "C" void kernel_launch(void* const* d_in, const int* in_sizes, int n_in,
                              void* d_out, int out_size, void* d_ws, size_t ws_size,
                              hipStream_t stream) {
    const float* xyz    = (const float*)d_in[0];
    const float* ec1_w  = (const float*)d_in[1];
    const float* ec1_s  = (const float*)d_in[2];
    const float* ec1_t  = (const float*)d_in[3];
    const float* ec2_w  = (const float*)d_in[4];
    const float* ec2_s  = (const float*)d_in[5];
    const float* ec2_t  = (const float*)d_in[6];
    const float* ec3_w  = (const float*)d_in[7];
    const float* ec3_s  = (const float*)d_in[8];
    const float* ec3_t  = (const float*)d_in[9];
    const float* ec4_w  = (const float*)d_in[10];
    const float* ec4_s  = (const float*)d_in[11];
    const float* ec4_t  = (const float*)d_in[12];
    const float* fuse_w = (const float*)d_in[13];
    const float* fuse_s = (const float*)d_in[14];
    const float* fuse_t = (const float*)d_in[15];
    const float* emb_w  = (const float*)d_in[16];
    const float* emb_s  = (const float*)d_in[17];
    const float* emb_t  = (const float*)d_in[18];
    const float* h1_w   = (const float*)d_in[19];
    const float* h1_s   = (const float*)d_in[20];
    const float* h1_t   = (const float*)d_in[21];
    const float* h2_w   = (const float*)d_in[22];
    const float* h2_s   = (const float*)d_in[23];
    const float* h2_t   = (const float*)d_in[24];
    const float* h3_w   = (const float*)d_in[25];
    const float* h3_b   = (const float*)d_in[26];
    float* out = (float*)d_out;

    float* ws = (float*)d_ws;
    size_t off = 0;
    float* xcat = ws + off; off += (size_t)M_ * 512;
    float* xloc = ws + off; off += (size_t)M_ * 512;
    float* yz   = ws + off; off += (size_t)M_ * 512;
    float* xt   = ws + off; off += (size_t)B_ * 128 * N_;
    float* xx   = ws + off; off += M_;
    int*   idx  = (int*)(ws + off); off += (size_t)M_ * KNN;
    float* ws1  = ws + off; off += 2 * 64 * 16;
    float* ws2  = ws + off; off += 2 * 64 * 64;
    float* ws3  = ws + off; off += 2 * 128 * 64;
    unsigned* gmax = (unsigned*)(ws + off); off += B_ * 1024;
    float* corr = ws + off; off += B_ * 256;
    unsigned short* fuse_h = (unsigned short*)(ws + off); off += 512 * 512 / 2;
    unsigned short* fuse_l = (unsigned short*)(ws + off); off += 512 * 512 / 2;
    unsigned short* emb_h  = (unsigned short*)(ws + off); off += 1024 * 512 / 2;
    unsigned short* emb_l  = (unsigned short*)(ws + off); off += 1024 * 512 / 2;
    unsigned short* h1_h   = (unsigned short*)(ws + off); off += 256 * 512 / 2;
    unsigned short* h1_l   = (unsigned short*)(ws + off); off += 256 * 512 / 2;
    unsigned short* h2_h   = (unsigned short*)(ws + off); off += 256 * 256 / 2;
    unsigned short* h2_l   = (unsigned short*)(ws + off); off += 256 * 256 / 2;
    unsigned short* ws4_h  = (unsigned short*)(ws + off); off += 512 * 128 / 2;
    unsigned short* ws4_l  = (unsigned short*)(ws + off); off += 512 * 128 / 2;
    float* h1o  = yz;                       // reuse after ec4's edge_max
    float* h2o  = yz + (size_t)M_ * 256;

    // ---- all weight prep + gmax init in ONE launch
    prep_weights_kernel<<<4232, 256, 0, stream>>>(
        ec1_w, ec2_w, ec3_w, ec4_w, fuse_w, emb_w, h1_w, h2_w,
        ws1, ws2, ws3, ws4_h, ws4_l, fuse_h, fuse_l, emb_h, emb_l,
        h1_h, h1_l, h2_h, h2_l, gmax);

    // ---- EdgeConv 1: xyz (C=3) -> xcat[:, 0:64]   (fp32 path, exact)
    prep_kernel<3><<<M_ / 256, 256, 0, stream>>>(xyz, 3, xx, xt);
    dist_topk_kernel<3><<<M_ / RM, 512, 0, stream>>>(xt, xx, idx);
    gemm_kernel<128, 0, false><<<dim3(1, M_ / 128), 256, 0, stream>>>(xyz, 3, ws1, 16, yz, 128, nullptr, nullptr, nullptr, nullptr, 3, 128);
    edge_max_kernel<<<(M_ * 16) / 256, 256, 0, stream>>>(yz, idx, ec1_s, ec1_t, xcat + 0, 512, 6);

    // ---- EdgeConv 2
    prep_kernel<64><<<M_ / 256, 256, 0, stream>>>(xcat + 0, 512, xx, xt);
    dist_topk_kernel<64><<<M_ / RM, 512, 0, stream>>>(xt, xx, idx);
    gemm_kernel<64, 0, true><<<dim3(2, M_ / 128), 256, 0, stream>>>(xcat + 0, 512, ws2, 64, yz, 128, nullptr, nullptr, nullptr, nullptr, 64, 128);
    edge_max_kernel<<<(M_ * 16) / 256, 256, 0, stream>>>(yz, idx, ec2_s, ec2_t, xcat + 64, 512, 6);

    // ---- EdgeConv 3
    prep_kernel<64><<<M_ / 256, 256, 0, stream>>>(xcat + 64, 512, xx, xt);
    dist_topk_kernel<64><<<M_ / RM, 512, 0, stream>>>(xt, xx, idx);
    gemm_kernel<128, 0, true><<<dim3(2, M_ / 128), 256, 0, stream>>>(xcat + 64, 512, ws3, 64, yz, 256, nullptr, nullptr, nullptr, nullptr, 64, 256);
    edge_max_kernel<<<(M_ * 32) / 256, 256, 0, stream>>>(yz, idx, ec3_s, ec3_t, xcat + 128, 512, 7);

    // ---- EdgeConv 4 (gemm output feeds no KNN -> MFMA-safe)
    prep_kernel<128><<<M_ / 256, 256, 0, stream>>>(xcat + 128, 512, xx, xt);
    dist_topk_kernel<128><<<M_ / RM, 512, 0, stream>>>(xt, xx, idx);
    mgemm_kernel<0><<<dim3(4, M_ / 128), 256, 0, stream>>>(xcat + 128, 512, ws4_h, ws4_l, 128, yz, 512, nullptr, nullptr, nullptr, nullptr, 128, 512);
    edge_max_kernel<<<(M_ * 64) / 256, 256, 0, stream>>>(yz, idx, ec4_s, ec4_t, xcat + 256, 512, 8);

    // ---- fuse: xcat(512) -> x_local(512), lrelu  [MFMA split-bf16]
    mgemm_kernel<1><<<dim3(4, M_ / 128), 256, 0, stream>>>(xcat, 512, fuse_h, fuse_l, 512, xloc, 512, fuse_s, fuse_t, nullptr, nullptr, 512, 512);

    // ---- emb: x_local -> (max over N) gmax  [MFMA split-bf16 + atomicMax]
    mgemm_kernel<3><<<dim3(8, M_ / 128), 256, 0, stream>>>(xloc, 512, emb_h, emb_l, 512, nullptr, 0, emb_s, emb_t, nullptr, gmax, 512, 1024);
    corr_kernel<<<512, 256, 0, stream>>>(gmax, h1_w, corr);

    // ---- h1: [x_local | glob] -> 256 ; glob part via corr  [MFMA]
    mgemm_kernel<1><<<dim3(2, M_ / 128), 256, 0, stream>>>(xloc, 512, h1_h, h1_l, 512, h1o, 256, h1_s, h1_t, corr, nullptr, 512, 256);
    // ---- h2: 256 -> 256  [MFMA]
    mgemm_kernel<1><<<dim3(2, M_ / 128), 256, 0, stream>>>(h1o, 256, h2_h, h2_l, 256, h2o, 256, h2_s, h2_t, nullptr, nullptr, 256, 256);
    // ---- h3: 256 -> 13 (+bias)  [fp32]
    gemm_kernel<64, 2, true><<<dim3(1, M_ / 128), 256, 0, stream>>>(h2o, 256, h3_w, 256, out, 13, nullptr, h3_b, nullptr, nullptr, 256, 13);
}

// Round 16
// 672.691 us; speedup vs baseline: 1.2010x; 1.0401x over previous
//
#include <hip/hip_runtime.h>

#define B_  8
#define N_  2048
#define M_  16384
#define KNN 20
#define NEG 0.2f

__device__ __forceinline__ unsigned enc_f(float f) {
    unsigned u = __float_as_uint(f);
    return (u & 0x80000000u) ? ~u : (u | 0x80000000u);
}
__device__ __forceinline__ float dec_f(unsigned u) {
    return (u & 0x80000000u) ? __uint_as_float(u & 0x7FFFFFFFu) : __uint_as_float(~u);
}
__device__ __forceinline__ unsigned long long mkkey(unsigned e, unsigned j) {
    return ((unsigned long long)e << 32) | j;
}
// bf16 round-to-nearest-even of fp32
__device__ __forceinline__ unsigned short bf_hi(float a) {
    unsigned u = __float_as_uint(a);
    unsigned r = u + 0x7FFFu + ((u >> 16) & 1u);
    return (unsigned short)(r >> 16);
}
__device__ __forceinline__ float bf_f(unsigned short h) {
    return __uint_as_float((unsigned)h << 16);
}

// ---------------- fused weight-prep mega-kernel ----------------
__device__ __forceinline__ void wstack_body(const float* __restrict__ w, float* __restrict__ ws,
                                            int O, int Cc, int Kp, int i) {
    if (i >= 2 * O * Kp) return;
    int row = i / Kp, k = i - row * Kp;
    float v = 0.f;
    if (k < Cc) {
        int o = (row < O) ? row : row - O;
        float w1 = w[(size_t)o * 2 * Cc + k];
        v = (row < O) ? w1 : (w[(size_t)o * 2 * Cc + Cc + k] - w1);
    }
    ws[i] = v;
}
__device__ __forceinline__ void wsplit_body(const float* __restrict__ w, int ldin,
                                            unsigned short* __restrict__ h, unsigned short* __restrict__ l,
                                            int Kshift, int i) {
    int row = i >> Kshift, k = i & ((1 << Kshift) - 1);
    float v = w[(size_t)row * ldin + k];
    unsigned short hi = bf_hi(v);
    h[i] = hi;
    l[i] = bf_hi(v - bf_f(hi));
}
// ec4 stacked weight, split directly (rows [0,256)=W1, [256,512)=W2-W1, K=128)
__device__ __forceinline__ void wstacksplit_body(const float* __restrict__ w,
                                                 unsigned short* __restrict__ h, unsigned short* __restrict__ l,
                                                 int i) {
    int row = i >> 7, k = i & 127;
    int o = (row < 256) ? row : row - 256;
    float w1 = w[(size_t)o * 256 + k];
    float v = (row < 256) ? w1 : (w[(size_t)o * 256 + 128 + k] - w1);
    unsigned short hi = bf_hi(v);
    h[i] = hi;
    l[i] = bf_hi(v - bf_f(hi));
}

__global__ void prep_weights_kernel(
        const float* __restrict__ ec1_w, const float* __restrict__ ec2_w,
        const float* __restrict__ ec3_w, const float* __restrict__ ec4_w,
        const float* __restrict__ fuse_w, const float* __restrict__ emb_w,
        const float* __restrict__ h1_w, const float* __restrict__ h2_w,
        float* __restrict__ ws1, float* __restrict__ ws2, float* __restrict__ ws3,
        unsigned short* __restrict__ ws4_h, unsigned short* __restrict__ ws4_l,
        unsigned short* __restrict__ fuse_h, unsigned short* __restrict__ fuse_l,
        unsigned short* __restrict__ emb_h, unsigned short* __restrict__ emb_l,
        unsigned short* __restrict__ h1_h, unsigned short* __restrict__ h1_l,
        unsigned short* __restrict__ h2_h, unsigned short* __restrict__ h2_l,
        unsigned* __restrict__ gmax) {
    int blk = blockIdx.x, tid = threadIdx.x;
    if (blk < 8)            { wstack_body(ec1_w, ws1, 64, 3, 16, blk * 256 + tid); }
    else if (blk < 40)      { wstack_body(ec2_w, ws2, 64, 64, 64, (blk - 8) * 256 + tid); }
    else if (blk < 104)     { wstack_body(ec3_w, ws3, 128, 64, 64, (blk - 40) * 256 + tid); }
    else if (blk < 360)     { wstacksplit_body(ec4_w, ws4_h, ws4_l, (blk - 104) * 256 + tid); }
    else if (blk < 1384)    { wsplit_body(fuse_w, 512, fuse_h, fuse_l, 9, (blk - 360) * 256 + tid); }
    else if (blk < 3432)    { wsplit_body(emb_w, 512, emb_h, emb_l, 9, (blk - 1384) * 256 + tid); }
    else if (blk < 3944)    { wsplit_body(h1_w, 1536, h1_h, h1_l, 9, (blk - 3432) * 256 + tid); }
    else if (blk < 4200)    { wsplit_body(h2_w, 256, h2_h, h2_l, 8, (blk - 3944) * 256 + tid); }
    else                    { int i = (blk - 4200) * 256 + tid;
                              if (i < B_ * 1024) gmax[i] = enc_f(-1e30f); }
}

// xx[m] = ||x_m||^2 ; xt[b][c][n] = x[m][c]
template<int C>
__global__ void prep_kernel(const float* __restrict__ x, int lda,
                            float* __restrict__ xx, float* __restrict__ xt) {
    int m = blockIdx.x * 256 + threadIdx.x;
    if (m >= M_) return;
    int b = m >> 11, n = m & 2047;
    const float* row = x + (size_t)m * lda;
    float s = 0.f;
#pragma unroll 8
    for (int c = 0; c < C; ++c) {
        float v = row[c];
        s = fmaf(v, v, s);
        xt[((size_t)b * C + c) * N_ + n] = v;
    }
    xx[m] = s;
}

// One block (512 thr) = 8 query rows; xi via wave-uniform scalar loads.
// Thread owns 4 CONTIGUOUS cols (j = 4*tid+p): the per-c streaming load is a
// single global_load_dwordx4 (16 B/lane coalescing sweet spot) instead of 4
// scattered dwords -- 4x fewer VMEM instrs + addr calcs. Key VALUES are
// bit-identical (same fmaf chain per element); only thread->col grouping
// changes, and the Tub bound argument (20 smallest lane-minima are keys
// <= Tub) holds for any grouping. acc[8][4] only, spill-proof.
#define RM 8
template<int C>
__global__ __launch_bounds__(512, 4) void dist_topk_kernel(
        const float* __restrict__ xt, const float* __restrict__ xx,
        int* __restrict__ idxout) {
    __shared__ unsigned m4s[RM][512];             // 16 KB
    __shared__ unsigned long long cand[RM][128];  // 8 KB
    __shared__ int cnt[RM];
    __shared__ unsigned tub[RM];
    int blk = blockIdx.x;
    int b = blk >> 8;
    int i0 = (blk & 255) * RM;
    int tid = threadIdx.x;
    int lane = tid & 63, r = tid >> 6;
    const float* xtb = xt + (size_t)b * C * N_;
    const float* xxb = xx + (size_t)b * N_;

    if (tid < RM) cnt[tid] = 0;
    __syncthreads();

    float xxir[RM];
#pragma unroll
    for (int q = 0; q < RM; ++q) xxir[q] = xxb[i0 + q];   // uniform -> s_load
    float xxj[4];
    *(float4*)&xxj[0] = *(const float4*)&xxb[4 * tid];

    // ---- compute: 4 contiguous cols/thread x 8 rows (fmaf chain asc. in c)
    float acc[RM][4];
#pragma unroll
    for (int q = 0; q < RM; ++q)
#pragma unroll
        for (int p = 0; p < 4; ++p) acc[q][p] = 0.f;

#pragma unroll 4
    for (int c = 0; c < C; ++c) {
        float xtv[4];
        *(float4*)&xtv[0] = *(const float4*)&xtb[(size_t)c * N_ + 4 * tid];
#pragma unroll
        for (int q = 0; q < RM; ++q) {
            float a = xtb[(size_t)c * N_ + i0 + q];       // uniform -> SGPR
#pragma unroll
            for (int p = 0; p < 4; ++p) acc[q][p] = fmaf(a, xtv[p], acc[q][p]);
        }
    }

    // ---- A: per-thread group min (keys recomputed, never stored)
#pragma unroll
    for (int q = 0; q < RM; ++q) {
        unsigned m = 0xFFFFFFFFu;
#pragma unroll
        for (int p = 0; p < 4; ++p) {
            unsigned e = enc_f(xxir[q] + xxj[p] - 2.f * acc[q][p]);
            m = (e < m) ? e : m;
        }
        m4s[q][tid] = m;
    }
    __syncthreads();

    // ---- B: Tub[r] = 20th-smallest lane-min (one live ballot per step)
    {
        unsigned lmin = 0xFFFFFFFFu;
#pragma unroll
        for (int i = 0; i < 8; ++i) {
            unsigned v = m4s[r][lane + 64 * i];
            lmin = (v < lmin) ? v : lmin;
        }
        unsigned T = 0u;
        for (int bpos = 31; bpos >= 0; --bpos) {
            unsigned cd = T | (1u << bpos);
            unsigned long long bal = __ballot(lmin < cd);
            if ((int)__popcll(bal) < KNN) T = cd;
        }
        if (lane == 0) tub[r] = T;
    }
    __syncthreads();

    // ---- C: append candidates (e <= Tub[row]); expected ~24 per row
#pragma unroll
    for (int q = 0; q < RM; ++q) {
        unsigned Tq = tub[q];
#pragma unroll
        for (int p = 0; p < 4; ++p) {
            unsigned e = enc_f(xxir[q] + xxj[p] - 2.f * acc[q][p]);
            if (e <= Tq) {
                int pos = atomicAdd(&cnt[q], 1);
                if (pos < 128)
                    cand[q][pos] = mkkey(e, (unsigned)(4 * tid + p));
            }
        }
    }
    __syncthreads();

    // ---- D: rank candidates; winners fill slots 0..19 exactly
    int A = cnt[r];
    if (A > 128) A = 128;   // unreachable on continuous data (guarded)
    int* orow = idxout + (size_t)(b * N_ + i0 + r) * KNN;
    for (int cc = lane; cc < A; cc += 64) {
        unsigned long long mykey = cand[r][cc];
        int rank = 0;
        for (int i = 0; i < A; ++i)
            rank += (cand[r][i] < mykey) ? 1 : 0;
        if (rank < KNN) orow[rank] = (int)(mykey & 2047u);
    }
}

// ---------------- MFMA split-bf16 GEMM ----------------
typedef __attribute__((ext_vector_type(8))) short short8;
typedef __attribute__((ext_vector_type(4))) float f32x4;

template<int MODE>
__global__ __launch_bounds__(256, 3) void mgemm_kernel(
        const float* __restrict__ A, int lda,
        const unsigned short* __restrict__ Bh, const unsigned short* __restrict__ Bl, int ldw,
        float* __restrict__ out, int ldo,
        const float* __restrict__ sc, const float* __restrict__ sh,
        const float* __restrict__ addvec, unsigned* __restrict__ gmax,
        int K, int O) {
    __shared__ unsigned short Ah_s[128][40];
    __shared__ unsigned short Al_s[128][40];
    __shared__ unsigned short Bh_s[128][40];
    __shared__ unsigned short Bl_s[128][40];
    int tid = threadIdx.x;
    int lane = tid & 63, w = tid >> 6;
    int ln = lane & 15, kg = lane >> 4;
    int wm = (w >> 1) * 64, wn = (w & 1) * 64;
    int m0 = blockIdx.y * 128, o0 = blockIdx.x * 128;
    f32x4 acc[4][4] = {};

    for (int k0 = 0; k0 < K; k0 += 32) {
#pragma unroll
        for (int j = 0; j < 4; ++j) {
            int s = tid + j * 256;
            int row = s >> 3, q = s & 7;
            float4 v = *(const float4*)&A[(size_t)(m0 + row) * lda + k0 + q * 4];
            unsigned short h0 = bf_hi(v.x), h1 = bf_hi(v.y), h2 = bf_hi(v.z), h3 = bf_hi(v.w);
            unsigned short l0 = bf_hi(v.x - bf_f(h0)), l1 = bf_hi(v.y - bf_f(h1));
            unsigned short l2 = bf_hi(v.z - bf_f(h2)), l3 = bf_hi(v.w - bf_f(h3));
            *(uint2*)&Ah_s[row][q * 4] = make_uint2((unsigned)h0 | ((unsigned)h1 << 16),
                                                    (unsigned)h2 | ((unsigned)h3 << 16));
            *(uint2*)&Al_s[row][q * 4] = make_uint2((unsigned)l0 | ((unsigned)l1 << 16),
                                                    (unsigned)l2 | ((unsigned)l3 << 16));
        }
#pragma unroll
        for (int j = 0; j < 2; ++j) {
            int s = tid + j * 256;
            int row = s >> 2, q = s & 3;
            *(uint4*)&Bh_s[row][q * 8] = *(const uint4*)&Bh[(size_t)(o0 + row) * ldw + k0 + q * 8];
            *(uint4*)&Bl_s[row][q * 8] = *(const uint4*)&Bl[(size_t)(o0 + row) * ldw + k0 + q * 8];
        }
        __syncthreads();

        short8 ah[4], al[4], bh[4], bl[4];
#pragma unroll
        for (int t = 0; t < 4; ++t) {
            ah[t] = *(const short8*)&Ah_s[wm + t * 16 + ln][kg * 8];
            al[t] = *(const short8*)&Al_s[wm + t * 16 + ln][kg * 8];
            bh[t] = *(const short8*)&Bh_s[wn + t * 16 + ln][kg * 8];
            bl[t] = *(const short8*)&Bl_s[wn + t * 16 + ln][kg * 8];
        }
#pragma unroll
        for (int t = 0; t < 4; ++t)
#pragma unroll
            for (int u = 0; u < 4; ++u) {
                acc[t][u] = __builtin_amdgcn_mfma_f32_16x16x32_bf16(ah[t], bh[u], acc[t][u], 0, 0, 0);
                acc[t][u] = __builtin_amdgcn_mfma_f32_16x16x32_bf16(ah[t], bl[u], acc[t][u], 0, 0, 0);
                acc[t][u] = __builtin_amdgcn_mfma_f32_16x16x32_bf16(al[t], bh[u], acc[t][u], 0, 0, 0);
            }
        __syncthreads();
    }

    int b = m0 >> 11;
    if constexpr (MODE == 3) {
#pragma unroll
        for (int u = 0; u < 4; ++u) {
            int o = o0 + wn + u * 16 + ln;
            float s = sc[o], t0 = sh[o];
            float cm = -1e30f;
#pragma unroll
            for (int t = 0; t < 4; ++t)
#pragma unroll
                for (int p = 0; p < 4; ++p) {
                    float v = fmaf(acc[t][u][p], s, t0);
                    v = (v >= 0.f) ? v : NEG * v;
                    cm = fmaxf(cm, v);
                }
            cm = fmaxf(cm, __shfl_xor(cm, 16));
            cm = fmaxf(cm, __shfl_xor(cm, 32));
            if (kg == 0) atomicMax(&gmax[b * 1024 + o], enc_f(cm));
        }
        return;
    }
#pragma unroll
    for (int t = 0; t < 4; ++t)
#pragma unroll
        for (int p = 0; p < 4; ++p) {
            int m = m0 + wm + t * 16 + kg * 4 + p;
#pragma unroll
            for (int u = 0; u < 4; ++u) {
                int o = o0 + wn + u * 16 + ln;
                float v = acc[t][u][p];
                if (MODE == 1) {
                    if (addvec) v += addvec[b * O + o];
                    v = fmaf(v, sc[o], sh[o]);
                    v = (v >= 0.f) ? v : NEG * v;
                }
                out[(size_t)m * ldo + o] = v;
            }
        }
}

// ---------------- fp32 GEMM (ec1..ec3, h3) ----------------
template<int TN, int MODE, bool VEC>
__global__ __launch_bounds__(256, 4) void gemm_kernel(
        const float* __restrict__ A, int lda,
        const float* __restrict__ W, int ldw,
        float* __restrict__ out, int ldo,
        const float* __restrict__ sc, const float* __restrict__ sh,
        const float* __restrict__ addvec, unsigned* __restrict__ gmax,
        int K, int O) {
    constexpr int TM = 128;
    constexpr int JN = TN / 16;
    __shared__ float As[16][TM];
    __shared__ float Bs[16][TN];
    int tid = threadIdx.x;
    int tx = tid & 15, ty = tid >> 4;
    int o0 = blockIdx.x * TN, m0 = blockIdx.y * TM;
    float acc[8][JN] = {};

    for (int k0 = 0; k0 < K; k0 += 16) {
        if constexpr (VEC) {
#pragma unroll
            for (int s = 0; s < 2; ++s) {
                int t = tid + s * 256;
                int row = t >> 2, c4 = (t & 3) << 2;
                float4 v = *(const float4*)&A[(size_t)(m0 + row) * lda + k0 + c4];
                As[c4 + 0][row] = v.x; As[c4 + 1][row] = v.y;
                As[c4 + 2][row] = v.z; As[c4 + 3][row] = v.w;
            }
#pragma unroll
            for (int s = 0; s < TN / 64; ++s) {
                int t = tid + s * 256;
                int row = t >> 2, c4 = (t & 3) << 2;
                int o = o0 + row;
                float4 v = make_float4(0.f, 0.f, 0.f, 0.f);
                if (o < O) v = *(const float4*)&W[(size_t)o * ldw + k0 + c4];
                Bs[c4 + 0][row] = v.x; Bs[c4 + 1][row] = v.y;
                Bs[c4 + 2][row] = v.z; Bs[c4 + 3][row] = v.w;
            }
        } else {
            for (int t = tid; t < TM * 16; t += 256) {
                int row = t >> 4, k = t & 15;
                As[k][row] = (k0 + k < K) ? A[(size_t)(m0 + row) * lda + k0 + k] : 0.f;
            }
            for (int t = tid; t < TN * 16; t += 256) {
                int row = t >> 4, k = t & 15;
                Bs[k][row] = W[(size_t)(o0 + row) * ldw + k0 + k];
            }
        }
        __syncthreads();
#pragma unroll
        for (int kk = 0; kk < 16; ++kk) {
            float a[8], bv[JN];
            *(float4*)&a[0] = *(const float4*)&As[kk][ty * 8];
            *(float4*)&a[4] = *(const float4*)&As[kk][ty * 8 + 4];
            *(float4*)&bv[0] = *(const float4*)&Bs[kk][tx * JN];
            if (JN == 8) *(float4*)&bv[4] = *(const float4*)&Bs[kk][tx * JN + 4];
#pragma unroll
            for (int i = 0; i < 8; ++i)
#pragma unroll
                for (int j = 0; j < JN; ++j)
                    acc[i][j] = fmaf(a[i], bv[j], acc[i][j]);
        }
        __syncthreads();
    }

    int b = m0 >> 11;
    bool fullstore = (o0 + TN <= O) && ((ldo & 3) == 0);
#pragma unroll
    for (int i = 0; i < 8; ++i) {
        int m = m0 + ty * 8 + i;
        float vals[JN];
#pragma unroll
        for (int j = 0; j < JN; ++j) {
            int o = o0 + tx * JN + j;
            float v = acc[i][j];
            if (MODE == 1) {
                if (addvec) v += addvec[b * O + o];
                v = fmaf(v, sc[o], sh[o]);
                v = (v >= 0.f) ? v : NEG * v;
            } else if (MODE == 2) {
                v += sh[o];
            }
            vals[j] = v;
        }
        if (fullstore) {
#pragma unroll
            for (int j0 = 0; j0 < JN; j0 += 4)
                *(float4*)&out[(size_t)m * ldo + o0 + tx * JN + j0] = *(float4*)&vals[j0];
        } else {
#pragma unroll
            for (int j = 0; j < JN; ++j) {
                int o = o0 + tx * JN + j;
                if (o < O) out[(size_t)m * ldo + o] = vals[j];
            }
        }
    }
}

// out[m][o..o+3] = max_k lrelu((y[nbr_k] + z[m]) * sc + sh); y/z packed in yz.
__global__ void edge_max_kernel(const float* __restrict__ yz, const int* __restrict__ idx,
                                const float* __restrict__ sc, const float* __restrict__ sh,
                                float* __restrict__ out, int ldo, int oshift) {
    int gid = blockIdx.x * 256 + threadIdx.x;
    int O = 1 << oshift;
    int m = gid >> (oshift - 2);
    int o = (gid & ((1 << (oshift - 2)) - 1)) << 2;
    int ldyz = 2 * O;
    float4 z = *(const float4*)&yz[(size_t)m * ldyz + O + o];
    float4 s4 = *(const float4*)&sc[o];
    float4 t4 = *(const float4*)&sh[o];
    const int* ip = idx + (size_t)m * KNN;
    int bbase = m & ~(N_ - 1);
    float4 mv = make_float4(-1e30f, -1e30f, -1e30f, -1e30f);
#pragma unroll
    for (int kk = 0; kk < KNN; ++kk) {
        int j = ip[kk];
        float4 y = *(const float4*)&yz[(size_t)(bbase + j) * ldyz + o];
        float v;
        v = fmaf(y.x + z.x, s4.x, t4.x); v = (v >= 0.f) ? v : NEG * v; mv.x = fmaxf(mv.x, v);
        v = fmaf(y.y + z.y, s4.y, t4.y); v = (v >= 0.f) ? v : NEG * v; mv.y = fmaxf(mv.y, v);
        v = fmaf(y.z + z.z, s4.z, t4.z); v = (v >= 0.f) ? v : NEG * v; mv.z = fmaxf(mv.z, v);
        v = fmaf(y.w + z.w, s4.w, t4.w); v = (v >= 0.f) ? v : NEG * v; mv.w = fmaxf(mv.w, v);
    }
    *(float4*)&out[(size_t)m * ldo + o] = mv;
}

// corr[b][o] = sum_c dec(gmax[b][c]) * h1w[o][512+c]   (decode folded in)
__global__ void corr_kernel(const unsigned* __restrict__ gmax, const float* __restrict__ h1w,
                            float* __restrict__ corr) {
    int wid = (blockIdx.x * 256 + threadIdx.x) >> 6;
    int lane = threadIdx.x & 63;
    int b = wid >> 8, o = wid & 255;
    const unsigned* g = gmax + b * 1024;
    const float* w = h1w + (size_t)o * 1536 + 512;
    float s = 0.f;
    for (int c = lane; c < 1024; c += 64) s = fmaf(dec_f(g[c]), w[c], s);
#pragma unroll
    for (int off = 32; off >= 1; off >>= 1) s += __shfl_xor(s, off);
    if (lane == 0) corr[b * 256 + o] = s;
}

extern "C" void kernel_launch(void* const* d_in, const int* in_sizes, int n_in,
                              void* d_out, int out_size, void* d_ws, size_t ws_size,
                              hipStream_t stream) {
    const float* xyz    = (const float*)d_in[0];
    const float* ec1_w  = (const float*)d_in[1];
    const float* ec1_s  = (const float*)d_in[2];
    const float* ec1_t  = (const float*)d_in[3];
    const float* ec2_w  = (const float*)d_in[4];
    const float* ec2_s  = (const float*)d_in[5];
    const float* ec2_t  = (const float*)d_in[6];
    const float* ec3_w  = (const float*)d_in[7];
    const float* ec3_s  = (const float*)d_in[8];
    const float* ec3_t  = (const float*)d_in[9];
    const float* ec4_w  = (const float*)d_in[10];
    const float* ec4_s  = (const float*)d_in[11];
    const float* ec4_t  = (const float*)d_in[12];
    const float* fuse_w = (const float*)d_in[13];
    const float* fuse_s = (const float*)d_in[14];
    const float* fuse_t = (const float*)d_in[15];
    const float* emb_w  = (const float*)d_in[16];
    const float* emb_s  = (const float*)d_in[17];
    const float* emb_t  = (const float*)d_in[18];
    const float* h1_w   = (const float*)d_in[19];
    const float* h1_s   = (const float*)d_in[20];
    const float* h1_t   = (const float*)d_in[21];
    const float* h2_w   = (const float*)d_in[22];
    const float* h2_s   = (const float*)d_in[23];
    const float* h2_t   = (const float*)d_in[24];
    const float* h3_w   = (const float*)d_in[25];
    const float* h3_b   = (const float*)d_in[26];
    float* out = (float*)d_out;

    float* ws = (float*)d_ws;
    size_t off = 0;
    float* xcat = ws + off; off += (size_t)M_ * 512;
    float* xloc = ws + off; off += (size_t)M_ * 512;
    float* yz   = ws + off; off += (size_t)M_ * 512;
    float* xt   = ws + off; off += (size_t)B_ * 128 * N_;
    float* xx   = ws + off; off += M_;
    int*   idx  = (int*)(ws + off); off += (size_t)M_ * KNN;
    float* ws1  = ws + off; off += 2 * 64 * 16;
    float* ws2  = ws + off; off += 2 * 64 * 64;
    float* ws3  = ws + off; off += 2 * 128 * 64;
    unsigned* gmax = (unsigned*)(ws + off); off += B_ * 1024;
    float* corr = ws + off; off += B_ * 256;
    unsigned short* fuse_h = (unsigned short*)(ws + off); off += 512 * 512 / 2;
    unsigned short* fuse_l = (unsigned short*)(ws + off); off += 512 * 512 / 2;
    unsigned short* emb_h  = (unsigned short*)(ws + off); off += 1024 * 512 / 2;
    unsigned short* emb_l  = (unsigned short*)(ws + off); off += 1024 * 512 / 2;
    unsigned short* h1_h   = (unsigned short*)(ws + off); off += 256 * 512 / 2;
    unsigned short* h1_l   = (unsigned short*)(ws + off); off += 256 * 512 / 2;
    unsigned short* h2_h   = (unsigned short*)(ws + off); off += 256 * 256 / 2;
    unsigned short* h2_l   = (unsigned short*)(ws + off); off += 256 * 256 / 2;
    unsigned short* ws4_h  = (unsigned short*)(ws + off); off += 512 * 128 / 2;
    unsigned short* ws4_l  = (unsigned short*)(ws + off); off += 512 * 128 / 2;
    float* h1o  = yz;                       // reuse after ec4's edge_max
    float* h2o  = yz + (size_t)M_ * 256;

    // ---- all weight prep + gmax init in ONE launch
    prep_weights_kernel<<<4232, 256, 0, stream>>>(
        ec1_w, ec2_w, ec3_w, ec4_w, fuse_w, emb_w, h1_w, h2_w,
        ws1, ws2, ws3, ws4_h, ws4_l, fuse_h, fuse_l, emb_h, emb_l,
        h1_h, h1_l, h2_h, h2_l, gmax);

    // ---- EdgeConv 1: xyz (C=3) -> xcat[:, 0:64]   (fp32 path, exact)
    prep_kernel<3><<<M_ / 256, 256, 0, stream>>>(xyz, 3, xx, xt);
    dist_topk_kernel<3><<<M_ / RM, 512, 0, stream>>>(xt, xx, idx);
    gemm_kernel<128, 0, false><<<dim3(1, M_ / 128), 256, 0, stream>>>(xyz, 3, ws1, 16, yz, 128, nullptr, nullptr, nullptr, nullptr, 3, 128);
    edge_max_kernel<<<(M_ * 16) / 256, 256, 0, stream>>>(yz, idx, ec1_s, ec1_t, xcat + 0, 512, 6);

    // ---- EdgeConv 2
    prep_kernel<64><<<M_ / 256, 256, 0, stream>>>(xcat + 0, 512, xx, xt);
    dist_topk_kernel<64><<<M_ / RM, 512, 0, stream>>>(xt, xx, idx);
    gemm_kernel<64, 0, true><<<dim3(2, M_ / 128), 256, 0, stream>>>(xcat + 0, 512, ws2, 64, yz, 128, nullptr, nullptr, nullptr, nullptr, 64, 128);
    edge_max_kernel<<<(M_ * 16) / 256, 256, 0, stream>>>(yz, idx, ec2_s, ec2_t, xcat + 64, 512, 6);

    // ---- EdgeConv 3
    prep_kernel<64><<<M_ / 256, 256, 0, stream>>>(xcat + 64, 512, xx, xt);
    dist_topk_kernel<64><<<M_ / RM, 512, 0, stream>>>(xt, xx, idx);
    gemm_kernel<128, 0, true><<<dim3(2, M_ / 128), 256, 0, stream>>>(xcat + 64, 512, ws3, 64, yz, 256, nullptr, nullptr, nullptr, nullptr, 64, 256);
    edge_max_kernel<<<(M_ * 32) / 256, 256, 0, stream>>>(yz, idx, ec3_s, ec3_t, xcat + 128, 512, 7);

    // ---- EdgeConv 4 (gemm output feeds no KNN -> MFMA-safe)
    prep_kernel<128><<<M_ / 256, 256, 0, stream>>>(xcat + 128, 512, xx, xt);
    dist_topk_kernel<128><<<M_ / RM, 512, 0, stream>>>(xt, xx, idx);
    mgemm_kernel<0><<<dim3(4, M_ / 128), 256, 0, stream>>>(xcat + 128, 512, ws4_h, ws4_l, 128, yz, 512, nullptr, nullptr, nullptr, nullptr, 128, 512);
    edge_max_kernel<<<(M_ * 64) / 256, 256, 0, stream>>>(yz, idx, ec4_s, ec4_t, xcat + 256, 512, 8);

    // ---- fuse: xcat(512) -> x_local(512), lrelu  [MFMA split-bf16]
    mgemm_kernel<1><<<dim3(4, M_ / 128), 256, 0, stream>>>(xcat, 512, fuse_h, fuse_l, 512, xloc, 512, fuse_s, fuse_t, nullptr, nullptr, 512, 512);

    // ---- emb: x_local -> (max over N) gmax  [MFMA split-bf16 + atomicMax]
    mgemm_kernel<3><<<dim3(8, M_ / 128), 256, 0, stream>>>(xloc, 512, emb_h, emb_l, 512, nullptr, 0, emb_s, emb_t, nullptr, gmax, 512, 1024);
    corr_kernel<<<512, 256, 0, stream>>>(gmax, h1_w, corr);

    // ---- h1: [x_local | glob] -> 256 ; glob part via corr  [MFMA]
    mgemm_kernel<1><<<dim3(2, M_ / 128), 256, 0, stream>>>(xloc, 512, h1_h, h1_l, 512, h1o, 256, h1_s, h1_t, corr, nullptr, 512, 256);
    // ---- h2: 256 -> 256  [MFMA]
    mgemm_kernel<1><<<dim3(2, M_ / 128), 256, 0, stream>>>(h1o, 256, h2_h, h2_l, 256, h2o, 256, h2_s, h2_t, nullptr, nullptr, 256, 256);
    // ---- h3: 256 -> 13 (+bias)  [fp32]
    gemm_kernel<64, 2, true><<<dim3(1, M_ / 128), 256, 0, stream>>>(h2o, 256, h3_w, 256, out, 13, nullptr, h3_b, nullptr, nullptr, 256, 13);
}